// Round 24
// baseline (556.554 us; speedup 1.0000x reference)
//
#include <hip/hip_runtime.h>
#include <hip/hip_bf16.h>

#define KNN_K 20
typedef _Float16 f16;
typedef _Float16 half8 __attribute__((ext_vector_type(8)));
typedef float f32x4 __attribute__((ext_vector_type(4)));

__device__ __forceinline__ float lrelu(float x){ return x >= 0.f ? x : 0.2f*x; }
__device__ __forceinline__ f16 us2h(unsigned short u){ union{unsigned short u; f16 h;} x; x.u=u; return x.h; }
__device__ __forceinline__ unsigned short h2us(f16 h){ union{unsigned short u; f16 h;} x; x.h=h; return x.u; }

__device__ __forceinline__ unsigned pack_key16(f16 v, int m){
  unsigned u = h2us(v);
  unsigned s = (u & 0x8000u) ? ((~u) & 0xFFFFu) : (u | 0x8000u);
  return (s << 16) | ((~(unsigned)m) & 0xFFFFu);
}

__device__ __forceinline__ unsigned med3u(unsigned a, unsigned b, unsigned c){
  unsigned d;
  asm("v_med3_u32 %0, %1, %2, %3" : "=v"(d) : "v"(a), "v"(b), "v"(c));
  return d;
}

// Sorted-desc insert via median: tk'[j] = med3(tk[j-1], tk[j], key), reverse order
// (reads see OLD values; depth-1 dependencies; 20 ops). Exact.
__device__ __forceinline__ void insert_nc(unsigned* tk, unsigned key){
  #pragma unroll
  for (int j=KNN_K-1; j>=1; --j)
    tk[j] = med3u(tk[j-1], tk[j], key);
  tk[0] = max(tk[0], key);
}

__device__ __forceinline__ void merge_sorted(unsigned* tk, const unsigned* src){
  #pragma unroll
  for (int j=0;j<KNN_K;++j){
    unsigned key = src[j];
    if (key <= tk[KNN_K-1]) break;
    insert_nc(tk, key);
  }
}

// ---------------- prep0: x0 build + round-1 UV (fused) + all weight transposes ----------------
__global__ __launch_bounds__(256) void prep0(
    const float* __restrict__ pos, const int* __restrict__ nt,
    unsigned short* __restrict__ xh0, unsigned short* __restrict__ xx0, int N,
    const float* __restrict__ W1, const float* __restrict__ bn1,
    float* __restrict__ Ut, float* __restrict__ Vtb,
    const float* __restrict__ W6, float* __restrict__ w6t,
    const float* __restrict__ W7, float* __restrict__ w7xt,
    const float* __restrict__ W8, float* __restrict__ w8t)
{
  __shared__ float Wd[64][12], Wf[64][12];
  __shared__ float t1s[64], b1s[64], m1s[64];
  int b = blockIdx.x, tid = threadIdx.x;
  int nb0 = (N + 255) >> 8;
  if (b < nb0){
    // stage W1-derived weights + bn1 transform
    for (int i = tid; i < 768; i += 256){
      int o = i / 12, c = i % 12;
      float wd = W1[(size_t)o*24 + c];
      Wd[o][c] = wd;
      Wf[o][c] = W1[(size_t)o*24 + 12 + c] - wd;
    }
    if (tid < 64){
      t1s[tid] = bn1[tid] / sqrtf(bn1[192+tid] + 1e-5f);
      b1s[tid] = bn1[64+tid];
      m1s[tid] = bn1[128+tid];
    }
    __syncthreads();
    int n = b*256 + tid;
    float v[12];
    v[0]=pos[n*3+0]; v[1]=pos[n*3+1]; v[2]=pos[n*3+2];
    int t = nt[n];
    #pragma unroll
    for (int c=0;c<9;++c) v[3+c] = (t==c) ? 1.f : 0.f;
    float xa = 0.f;
    #pragma unroll
    for (int c=0;c<12;++c){
      f16 h = (f16)v[c];
      float hf = (float)h;
      xh0[(size_t)n*32+c] = h2us(h);
      f16 pe = (f16)(hf*hf);
      xa += (float)pe;
    }
    #pragma unroll
    for (int c=12;c<32;++c) xh0[(size_t)n*32+c] = 0;
    xx0[n] = h2us((f16)xa);
    // fused round-1 UV (identical accumulation order & bn transform as uv_kernel)
    #pragma unroll 1
    for (int ob4=0; ob4<4; ++ob4){
      float aU[16], aV[16];
      #pragma unroll
      for (int i=0;i<16;++i){ aU[i]=0.f; aV[i]=0.f; }
      #pragma unroll 4
      for (int c2=0;c2<12;++c2){
        float xv = v[c2];
        #pragma unroll
        for (int i=0;i<16;++i){
          aU[i] = fmaf(Wd[ob4*16+i][c2], xv, aU[i]);
          aV[i] = fmaf(Wf[ob4*16+i][c2], xv, aV[i]);
        }
      }
      #pragma unroll
      for (int i=0;i<16;++i){
        int o = ob4*16 + i;
        float tt = t1s[o];
        Ut[(size_t)n*64 + o]  = aU[i]*tt;
        Vtb[(size_t)n*64 + o] = fmaf(aV[i] - m1s[o], tt, b1s[o]);
      }
    }
    return;
  }
  b -= nb0;
  if (b < 768){
    int i = b*256 + tid;
    int o = i / 192, c = i % 192;
    w6t[(size_t)c*1024 + o] = W6[(size_t)o*192 + c];
    return;
  }
  b -= 768;
  if (b < 384){
    int i = b*256 + tid;
    int o = i / 192, c = i % 192;
    w7xt[(size_t)c*512 + o] = W7[(size_t)o*1216 + 1024 + c];
    return;
  }
  b -= 384;
  {
    int i = b*256 + tid;
    int o = i / 512, c = i % 512;
    w8t[(size_t)c*256 + o] = W8[(size_t)o*512 + c];
  }
}

// ---------------- fused MFMA kNN: single pass + med3 chain + intra-wave butterfly merge ----------------
template<int C>
__global__ __launch_bounds__(512) void knn_mfma(
    const unsigned short* __restrict__ xh,
    const unsigned short* __restrict__ xx,
    int* __restrict__ idx, int N)
{
  __shared__ unsigned lists[8][16][KNN_K];    // 10240 B (one wave-merged list per wave)
  __shared__ unsigned short xxs[8192];        // 16384 B
  int tid = threadIdx.x;
  int w = tid >> 6, lane = tid & 63;
  int g = lane >> 4, c = lane & 15;
  int n0 = blockIdx.x * 16;
  int ntiles = N >> 6;

  ((uint4*)xxs)[tid]       = ((const uint4*)xx)[tid];
  ((uint4*)xxs)[tid + 512] = ((const uint4*)xx)[tid + 512];

  half8 bfrag[C/32];
  #pragma unroll
  for (int kc=0; kc<C/32; ++kc)
    bfrag[kc] = *reinterpret_cast<const half8*>(xh + (size_t)(n0 + c)*C + kc*32 + g*8);
  f16 qxx = us2h(xx[n0 + c]);
  __syncthreads();

  unsigned tk[KNN_K];
  #pragma unroll
  for (int j=0;j<KNN_K;++j) tk[j] = 0u;

  const unsigned short* ap = xh + (size_t)(w*64 + c)*C + g*8;
  int ml = w*64 + g*4;

  for (int t = w; t < ntiles; t += 8){
    #pragma unroll
    for (int msub=0; msub<4; ++msub){
      const unsigned short* ap2 = ap + msub*(16*C);
      f32x4 acc = {0.f,0.f,0.f,0.f};
      #pragma unroll
      for (int kc=0; kc<C/32; ++kc){
        half8 af = *reinterpret_cast<const half8*>(ap2 + kc*32);
        acc = __builtin_amdgcn_mfma_f32_16x16x32_f16(af, bfrag[kc], acc, 0, 0, 0);
      }
      #pragma unroll
      for (int j=0;j<4;++j){
        int mloc = ml + msub*16 + j;
        f16 dh = (f16)acc[j];
        f16 mi = dh * (f16)(-2.0f);
        f16 xm = us2h(xxs[mloc]);
        f16 t1 = (-xm) - mi;
        f16 pdh = t1 - qxx;
        insert_nc(tk, pack_key16(pdh, mloc));
      }
    }
    ap += (size_t)512*C;
    ml += 512;
  }

  // intra-wave butterfly merge across g (snapshot partner, then merge — exact; r16-proven)
  {
    unsigned tmp[KNN_K];
    #pragma unroll
    for (int j=0;j<KNN_K;++j) tmp[j] = (unsigned)__shfl_xor((int)tk[j], 32, 64);
    merge_sorted(tk, tmp);
    #pragma unroll
    for (int j=0;j<KNN_K;++j) tmp[j] = (unsigned)__shfl_xor((int)tk[j], 16, 64);
    merge_sorted(tk, tmp);
  }
  if (lane < 16){
    unsigned* dst = lists[w][c];
    #pragma unroll
    for (int j=0;j<KNN_K;++j) dst[j] = tk[j];
  }
  __syncthreads();

  // block merge in wave 0 (lockstep: all loads precede later stores in program order)
  if (tid < 32){
    int n = tid >> 1, h = tid & 1;
    unsigned tk2[KNN_K];
    #pragma unroll
    for (int j=0;j<KNN_K;++j) tk2[j] = lists[h*4][n][j];
    for (int li=1; li<4; ++li) merge_sorted(tk2, lists[h*4 + li][n]);
    unsigned* dst = lists[h][n];
    #pragma unroll
    for (int j=0;j<KNN_K;++j) dst[j] = tk2[j];
  }
  if (tid < 16){
    int n = tid;
    unsigned tk2[KNN_K];
    #pragma unroll
    for (int j=0;j<KNN_K;++j) tk2[j] = lists[0][n][j];
    merge_sorted(tk2, lists[1][n]);
    #pragma unroll
    for (int j=0;j<KNN_K;++j)
      idx[(size_t)(n0 + n)*KNN_K + j] = (int)((~tk2[j]) & 0xFFFFu);
  }
}

// ---------------- edge conv v5: 4 q's per wave ----------------
template<bool SECOND>
__global__ __launch_bounds__(256) void edge2(
    const float* __restrict__ Ut, const float* __restrict__ Vtb,
    const int* __restrict__ idx,
    const float* __restrict__ W2, const float* __restrict__ bn2,
    float* __restrict__ outCN, unsigned short* __restrict__ outh,
    unsigned short* __restrict__ outxx, int N,
    const float* __restrict__ Wn, const float* __restrict__ bnn,
    float* __restrict__ UtN, float* __restrict__ VtbN)
{
  __shared__ float eb[4][4][64];
  __shared__ float xb[16][64];
  int w = threadIdx.x >> 6, o = threadIdx.x & 63;
  float w2r[64]; float t2=0.f,b2=0.f,m2=0.f;
  if (SECOND){
    #pragma unroll
    for (int c4=0;c4<16;++c4){
      float4 wv = *reinterpret_cast<const float4*>(W2 + (size_t)o*64 + c4*4);
      w2r[c4*4+0]=wv.x; w2r[c4*4+1]=wv.y; w2r[c4*4+2]=wv.z; w2r[c4*4+3]=wv.w;
    }
    t2 = bn2[o]/sqrtf(bn2[192+o]+1e-5f); b2 = bn2[64+o]; m2 = bn2[128+o];
  }
  int nq = blockIdx.x*16 + w*4;
  float vo[4], u[4], best[4];
  const int* ip[4];
  int jj[4];
  #pragma unroll
  for (int q=0;q<4;++q){
    vo[q] = Vtb[(size_t)(nq+q)*64 + o];
    ip[q] = idx + (size_t)(nq+q)*KNN_K;
    jj[q] = ip[q][0];
    u[q]  = Ut[(size_t)jj[q]*64 + o];
    best[q] = -INFINITY;
  }
  #pragma unroll 1
  for (int k=0;k<KNN_K;++k){
    float uc[4];
    #pragma unroll
    for (int q=0;q<4;++q) uc[q] = u[q];
    if (k < KNN_K-1){
      #pragma unroll
      for (int q=0;q<4;++q){ jj[q] = ip[q][k+1]; u[q] = Ut[(size_t)jj[q]*64 + o]; }
    }
    float e[4];
    #pragma unroll
    for (int q=0;q<4;++q) e[q] = lrelu(uc[q] + vo[q]);
    if (SECOND){
      #pragma unroll
      for (int q=0;q<4;++q) eb[q][w][o] = e[q];
      float s0[4], s1[4], s2[4], s3[4];
      #pragma unroll
      for (int q=0;q<4;++q){ s0[q]=0.f; s1[q]=0.f; s2[q]=0.f; s3[q]=0.f; }
      #pragma unroll
      for (int c4=0;c4<16;++c4){
        #pragma unroll
        for (int q=0;q<4;++q){
          float4 ev = *reinterpret_cast<const float4*>(eb[q][w] + c4*4);
          s0[q] = fmaf(w2r[c4*4+0], ev.x, s0[q]);
          s1[q] = fmaf(w2r[c4*4+1], ev.y, s1[q]);
          s2[q] = fmaf(w2r[c4*4+2], ev.z, s2[q]);
          s3[q] = fmaf(w2r[c4*4+3], ev.w, s3[q]);
        }
      }
      #pragma unroll
      for (int q=0;q<4;++q){
        float s = (s0[q]+s1[q])+(s2[q]+s3[q]);
        best[q] = fmaxf(best[q], lrelu(fmaf(s - m2, t2, b2)));
      }
    } else {
      #pragma unroll
      for (int q=0;q<4;++q) best[q] = fmaxf(best[q], e[q]);
    }
  }
  #pragma unroll
  for (int q=0;q<4;++q) outCN[(size_t)o*N + nq + q] = best[q];
  if (SECOND){
    float p[4];
    #pragma unroll
    for (int q=0;q<4;++q){
      f16 h = (f16)best[q]; float hf = (float)h;
      outh[(size_t)(nq+q)*64 + o] = h2us(h);
      p[q] = (float)(f16)(hf*hf);
    }
    #pragma unroll
    for (int s2s=32;s2s>=1;s2s>>=1){
      #pragma unroll
      for (int q=0;q<4;++q) p[q] += __shfl_xor(p[q], s2s, 64);
    }
    if (o == 0){
      #pragma unroll
      for (int q=0;q<4;++q) outxx[nq+q] = h2us((f16)p[q]);
    }
    if (Wn){
      #pragma unroll
      for (int q=0;q<4;++q) xb[w*4+q][o] = best[q];
      float tn = bnn[o]/sqrtf(bnn[192+o]+1e-5f);
      float bb = bnn[64+o], mm = bnn[128+o];
      const float* wr = Wn + (size_t)o*128;
      float aU[4], aV[4];
      #pragma unroll
      for (int q=0;q<4;++q){ aU[q]=0.f; aV[q]=0.f; }
      #pragma unroll 8
      for (int c=0;c<64;++c){
        float wd = wr[c], wc = wr[64+c];
        float wdf = wc - wd;
        #pragma unroll
        for (int q=0;q<4;++q){
          float xv = xb[w*4+q][c];
          aU[q] = fmaf(wd, xv, aU[q]);
          aV[q] = fmaf(wdf, xv, aV[q]);
        }
      }
      #pragma unroll
      for (int q=0;q<4;++q){
        UtN[(size_t)(nq+q)*64 + o]  = aU[q]*tn;
        VtbN[(size_t)(nq+q)*64 + o] = fmaf(aV[q] - mm, tn, bb);
      }
    }
  }
}

// ---------------- conv67: conv6 (bn6+lrelu+gmax) and conv7-raw merged ----------------
__global__ __launch_bounds__(256) void conv67(
    const float* __restrict__ w6t, const float* __restrict__ w7xt,
    const float* __restrict__ sA, const float* __restrict__ sB, const float* __restrict__ sC,
    const float* __restrict__ bn6,
    float* __restrict__ gpart, float* __restrict__ h7raw, int N)
{
  __shared__ float ws[2][32][68];
  int tid = threadIdx.x;
  int ln = tid & 63;
  int og = (tid >> 6) * 16;
  int n0 = blockIdx.x*128;
  int y = blockIdx.y;
  bool six = (y < 16);
  int O  = six ? 1024 : 512;
  int ob = six ? y*64 : (y-16)*64;
  const float* WT = six ? w6t : w7xt;
  int n = n0 + ln*2;
  float a0[16], a1[16];
  #pragma unroll
  for (int i=0;i<16;++i){ a0[i]=0.f; a1[i]=0.f; }

  auto stage = [&](int m, int buf){
    int c0 = m*32;
    #pragma unroll
    for (int r=0;r<8;++r){
      int i = r*256 + tid;
      int cc = i >> 6, oo = i & 63;
      ws[buf][cc][oo] = WT[(size_t)(c0+cc)*O + ob + oo];
    }
  };
  auto srcrow = [&](int crow)->const float*{
    if (crow < 64) return sA + (size_t)crow*N;
    crow -= 64;
    if (crow < 64) return sB + (size_t)crow*N;
    crow -= 64;
    return sC + (size_t)crow*N;
  };

  stage(0, 0);
  __syncthreads();
  #pragma unroll 1
  for (int m=0; m<6; ++m){
    int buf = m & 1;
    if (m+1 < 6) stage(m+1, buf^1);
    const float* srow = srcrow(m*32);
    #pragma unroll 4
    for (int cc=0; cc<32; ++cc){
      float2 xv = *reinterpret_cast<const float2*>(srow + (size_t)cc*N + n);
      const float* wr = &ws[buf][cc][og];
      #pragma unroll
      for (int i=0;i<16;++i){
        a0[i] = fmaf(wr[i], xv.x, a0[i]);
        a1[i] = fmaf(wr[i], xv.y, a1[i]);
      }
    }
    __syncthreads();
  }
  if (six){
    #pragma unroll
    for (int i=0;i<16;++i){
      int oG = ob + og + i;
      float t = bn6[oG] / sqrtf(bn6[3*1024+oG] + 1e-5f);
      float mm = bn6[2*1024+oG], bb = bn6[1*1024+oG];
      a0[i] = lrelu(fmaf(a0[i] - mm, t, bb));
      a1[i] = lrelu(fmaf(a1[i] - mm, t, bb));
      float v = fmaxf(a0[i], a1[i]);
      #pragma unroll
      for (int s=32;s>=1;s>>=1) v = fmaxf(v, __shfl_xor(v, s, 64));
      if (ln == 0) gpart[(size_t)oG*gridDim.x + blockIdx.x] = v;
    }
  } else {
    #pragma unroll
    for (int i=0;i<16;++i){
      float2 st = {a0[i], a1[i]};
      *reinterpret_cast<float2*>(h7raw + (size_t)(ob+og+i)*N + n) = st;
    }
  }
}

// ---------------- fused global-max + W7 g-bias ----------------
__global__ __launch_bounds__(1024) void gmax_bias7(
    const float* __restrict__ gpart, const float* __restrict__ W7,
    float* __restrict__ b7, int P)
{
  __shared__ float gs[1024];
  int t = threadIdx.x;
  float m = -INFINITY;
  for (int p=0;p<P;++p) m = fmaxf(m, gpart[(size_t)t*P + p]);
  gs[t] = m;
  __syncthreads();
  int w = t >> 6, ln = t & 63;
  #pragma unroll 1
  for (int oi=0; oi<32; ++oi){
    int o = w*32 + oi;
    float a = 0.f;
    #pragma unroll
    for (int c0=0; c0<1024; c0+=64)
      a = fmaf(W7[(size_t)o*1216 + c0 + ln], gs[c0 + ln], a);
    #pragma unroll
    for (int s=32;s>=1;s>>=1) a += __shfl_xor(a, s, 64);
    if (ln == 0) b7[o] = a;
  }
}

// ---------------- conv8 v2: o-tile 32 x n-tile 128, y-grid 8 ----------------
__global__ __launch_bounds__(256) void conv8w(
    const float* __restrict__ w8t,
    const float* __restrict__ h7raw,
    const float* __restrict__ b7, const float* __restrict__ bn7,
    const float* __restrict__ bn8,
    float* __restrict__ h8, int N)
{
  __shared__ float ws[2][32][36];
  __shared__ float e7s[512], t7s[512], mm7s[512], bb7s[512];
  int tid = threadIdx.x;
  int ln = tid & 63;
  int og = (tid >> 6) * 8;
  int n0 = blockIdx.x*128;
  int ob = blockIdx.y*32;
  int n = n0 + ln*2;
  for (int c = tid; c < 512; c += 256){
    t7s[c]  = bn7[c] / sqrtf(bn7[3*512+c] + 1e-5f);
    bb7s[c] = bn7[512+c];
    mm7s[c] = bn7[2*512+c];
    e7s[c]  = b7[c];
  }
  float a0[8], a1[8];
  #pragma unroll
  for (int i=0;i<8;++i){ a0[i]=0.f; a1[i]=0.f; }

  auto stage = [&](int m, int buf){
    int c0 = m*32;
    #pragma unroll
    for (int r=0;r<4;++r){
      int i = r*256 + tid;
      int cc = i >> 5, oo = i & 31;
      ws[buf][cc][oo] = w8t[(size_t)(c0+cc)*256 + ob + oo];
    }
  };

  stage(0, 0);
  __syncthreads();
  #pragma unroll 1
  for (int m=0; m<16; ++m){
    int buf = m & 1;
    if (m+1 < 16) stage(m+1, buf^1);
    int c0 = m*32;
    #pragma unroll 4
    for (int cc=0; cc<32; ++cc){
      int c = c0 + cc;
      float2 raw = *reinterpret_cast<const float2*>(h7raw + (size_t)c*N + n);
      float e = e7s[c], mm = mm7s[c], t = t7s[c], bb = bb7s[c];
      float xv0 = lrelu(fmaf((raw.x + e) - mm, t, bb));
      float xv1 = lrelu(fmaf((raw.y + e) - mm, t, bb));
      const float* wr = &ws[buf][cc][og];
      #pragma unroll
      for (int i=0;i<8;++i){
        a0[i] = fmaf(wr[i], xv0, a0[i]);
        a1[i] = fmaf(wr[i], xv1, a1[i]);
      }
    }
    __syncthreads();
  }
  #pragma unroll
  for (int i=0;i<8;++i){
    int oG = ob + og + i;
    float t = bn8[oG] / sqrtf(bn8[3*256+oG] + 1e-5f);
    float mm = bn8[2*256+oG], bb = bn8[256+oG];
    a0[i] = lrelu(fmaf(a0[i] - mm, t, bb));
    a1[i] = lrelu(fmaf(a1[i] - mm, t, bb));
    float2 st = {a0[i], a1[i]};
    *reinterpret_cast<float2*>(h8 + (size_t)oG*N + n) = st;
  }
}

__global__ __launch_bounds__(256) void w9_kernel(
    const float* __restrict__ W9, const float* __restrict__ h8, float* __restrict__ out, int N)
{
  int n = blockIdx.x*256 + threadIdx.x;
  if (n >= N) return;
  float a0=0.f, a1=0.f, a2=0.f;
  for (int c=0;c<256;++c){
    float xv = h8[(size_t)c*N + n];
    a0 = fmaf(W9[c],       xv, a0);
    a1 = fmaf(W9[256+c],   xv, a1);
    a2 = fmaf(W9[512+c],   xv, a2);
  }
  out[(size_t)n*3+0]=a0; out[(size_t)n*3+1]=a1; out[(size_t)n*3+2]=a2;
}

extern "C" void kernel_launch(void* const* d_in, const int* in_sizes, int n_in,
                              void* d_out, int out_size, void* d_ws, size_t ws_size,
                              hipStream_t stream) {
  const float* curr_pos = (const float*)d_in[0];
  const int*   node_t   = (const int*)  d_in[1];
  const float* W1 = (const float*)d_in[2];
  const float* W2 = (const float*)d_in[3];
  const float* W3 = (const float*)d_in[4];
  const float* W4 = (const float*)d_in[5];
  const float* W5 = (const float*)d_in[6];
  const float* W6 = (const float*)d_in[7];
  const float* W7 = (const float*)d_in[8];
  const float* W8 = (const float*)d_in[9];
  const float* W9 = (const float*)d_in[10];
  const float* bn1 = (const float*)d_in[11];
  const float* bn2 = (const float*)d_in[12];
  const float* bn3 = (const float*)d_in[13];
  const float* bn4 = (const float*)d_in[14];
  const float* bn5 = (const float*)d_in[15];
  const float* bn6 = (const float*)d_in[16];
  const float* bn7 = (const float*)d_in[17];
  const float* bn8 = (const float*)d_in[18];
  float* out = (float*)d_out;

  const int N = in_sizes[0] / 3;

  char* ws = (char*)d_ws;
  size_t off = 0;
  auto A = [&](size_t b){ size_t o = off; off = (o + b + 255) & ~(size_t)255; return o; };

  unsigned short* xh0 = (unsigned short*)(ws + A((size_t)N*32*2));
  unsigned short* xx0 = (unsigned short*)(ws + A((size_t)N*2));
  float* x1CN = (float*)(ws + A((size_t)N*64*4));
  unsigned short* xh1 = (unsigned short*)(ws + A((size_t)N*64*2));
  unsigned short* xx1 = (unsigned short*)(ws + A((size_t)N*2));
  float* x2CN = (float*)(ws + A((size_t)N*64*4));
  unsigned short* xh2 = (unsigned short*)(ws + A((size_t)N*64*2));
  unsigned short* xx2 = (unsigned short*)(ws + A((size_t)N*2));
  float* x3CN = (float*)(ws + A((size_t)N*64*4));
  int* idxb = (int*)(ws + A((size_t)N*KNN_K*4));
  float* Ut  = (float*)(ws + A((size_t)N*64*4));
  float* Vtb = (float*)(ws + A((size_t)N*64*4));
  float* Ut2  = (float*)(ws + A((size_t)N*64*4));
  float* Vtb2 = (float*)(ws + A((size_t)N*64*4));
  float* w6t  = (float*)(ws + A((size_t)192*1024*4));
  float* w7xt = (float*)(ws + A((size_t)192*512*4));
  float* w8t  = (float*)(ws + A((size_t)512*256*4));
  float* gpart= (float*)(ws + A((size_t)1024*(N/64)*4));
  float* b7   = (float*)(ws + A((size_t)512*4));
  float* h7raw= (float*)(ws + A((size_t)512*N*4));
  float* h8   = (float*)(ws + A((size_t)256*N*4));
  if (off > ws_size) return;

  dim3 b256(256), b512(512);
  int nb0 = (N + 255) / 256;
  prep0<<<dim3(nb0 + 768 + 384 + 512), b256, 0, stream>>>(
      curr_pos, node_t, xh0, xx0, N, W1, bn1, Ut, Vtb, W6, w6t, W7, w7xt, W8, w8t);

  dim3 gknn(N/16);
  dim3 gec(N/16);
  dim3 gfin((N+255)/256);

  // round 1  (edge2 epilogue computes UV for round 2 from x1/W3/bn3)
  knn_mfma<32><<<gknn, b512, 0, stream>>>(xh0, xx0, idxb, N);
  edge2<true><<<gec, b256, 0, stream>>>(Ut, Vtb, idxb, W2, bn2, x1CN, xh1, xx1, N, W3, bn3, Ut2, Vtb2);
  // round 2
  knn_mfma<64><<<gknn, b512, 0, stream>>>(xh1, xx1, idxb, N);
  edge2<true><<<gec, b256, 0, stream>>>(Ut2, Vtb2, idxb, W4, bn4, x2CN, xh2, xx2, N, W5, bn5, Ut, Vtb);
  // round 3
  knn_mfma<64><<<gknn, b512, 0, stream>>>(xh2, xx2, idxb, N);
  edge2<false><<<gec, b256, 0, stream>>>(Ut, Vtb, idxb, nullptr, nullptr, x3CN, nullptr, nullptr, N, nullptr, nullptr, nullptr, nullptr);
  // head
  conv67<<<dim3(N/128, 24), b256, 0, stream>>>(w6t, w7xt, x1CN, x2CN, x3CN, bn6, gpart, h7raw, N);
  gmax_bias7<<<dim3(1), dim3(1024), 0, stream>>>(gpart, W7, b7, N/128);
  conv8w<<<dim3(N/128, 8), b256, 0, stream>>>(w8t, h7raw, b7, bn7, bn8, h8, N);
  w9_kernel<<<gfin, b256, 0, stream>>>(W9, h8, out, N);
}

// Round 25
// 541.819 us; speedup vs baseline: 1.0272x; 1.0272x over previous
//
#include <hip/hip_runtime.h>
#include <hip/hip_bf16.h>

#define KNN_K 20
typedef _Float16 f16;
typedef _Float16 half8 __attribute__((ext_vector_type(8)));
typedef float f32x4 __attribute__((ext_vector_type(4)));

__device__ __forceinline__ float lrelu(float x){ return x >= 0.f ? x : 0.2f*x; }
__device__ __forceinline__ f16 us2h(unsigned short u){ union{unsigned short u; f16 h;} x; x.u=u; return x.h; }
__device__ __forceinline__ unsigned short h2us(f16 h){ union{unsigned short u; f16 h;} x; x.h=h; return x.u; }

__device__ __forceinline__ unsigned pack_key16(f16 v, int m){
  unsigned u = h2us(v);
  unsigned s = (u & 0x8000u) ? ((~u) & 0xFFFFu) : (u | 0x8000u);
  return (s << 16) | ((~(unsigned)m) & 0xFFFFu);
}

__device__ __forceinline__ unsigned med3u(unsigned a, unsigned b, unsigned c){
  unsigned d;
  asm("v_med3_u32 %0, %1, %2, %3" : "=v"(d) : "v"(a), "v"(b), "v"(c));
  return d;
}

// Sorted-desc insert via median: tk'[j] = med3(tk[j-1], tk[j], key), reverse order
// (reads see OLD values; depth-1 dependencies; 20 ops). Exact.
__device__ __forceinline__ void insert_nc(unsigned* tk, unsigned key){
  #pragma unroll
  for (int j=KNN_K-1; j>=1; --j)
    tk[j] = med3u(tk[j-1], tk[j], key);
  tk[0] = max(tk[0], key);
}

__device__ __forceinline__ void merge_sorted(unsigned* tk, const unsigned* src){
  #pragma unroll
  for (int j=0;j<KNN_K;++j){
    unsigned key = src[j];
    if (key <= tk[KNN_K-1]) break;
    insert_nc(tk, key);
  }
}

// ---------------- prep0: x0 build + round-1 UV (fused) + all weight transposes ----------------
__global__ __launch_bounds__(256) void prep0(
    const float* __restrict__ pos, const int* __restrict__ nt,
    unsigned short* __restrict__ xh0, unsigned short* __restrict__ xx0, int N,
    const float* __restrict__ W1, const float* __restrict__ bn1,
    float* __restrict__ Ut, float* __restrict__ Vtb,
    const float* __restrict__ W6, float* __restrict__ w6t,
    const float* __restrict__ W7, float* __restrict__ w7xt,
    const float* __restrict__ W8, float* __restrict__ w8t)
{
  __shared__ float Wd[64][12], Wf[64][12];
  __shared__ float t1s[64], b1s[64], m1s[64];
  int b = blockIdx.x, tid = threadIdx.x;
  int nb0 = (N + 255) >> 8;
  if (b < nb0){
    for (int i = tid; i < 768; i += 256){
      int o = i / 12, c = i % 12;
      float wd = W1[(size_t)o*24 + c];
      Wd[o][c] = wd;
      Wf[o][c] = W1[(size_t)o*24 + 12 + c] - wd;
    }
    if (tid < 64){
      t1s[tid] = bn1[tid] / sqrtf(bn1[192+tid] + 1e-5f);
      b1s[tid] = bn1[64+tid];
      m1s[tid] = bn1[128+tid];
    }
    __syncthreads();
    int n = b*256 + tid;
    float v[12];
    v[0]=pos[n*3+0]; v[1]=pos[n*3+1]; v[2]=pos[n*3+2];
    int t = nt[n];
    #pragma unroll
    for (int c=0;c<9;++c) v[3+c] = (t==c) ? 1.f : 0.f;
    float xa = 0.f;
    #pragma unroll
    for (int c=0;c<12;++c){
      f16 h = (f16)v[c];
      float hf = (float)h;
      xh0[(size_t)n*32+c] = h2us(h);
      f16 pe = (f16)(hf*hf);
      xa += (float)pe;
    }
    #pragma unroll
    for (int c=12;c<32;++c) xh0[(size_t)n*32+c] = 0;
    xx0[n] = h2us((f16)xa);
    #pragma unroll 1
    for (int ob4=0; ob4<4; ++ob4){
      float aU[16], aV[16];
      #pragma unroll
      for (int i=0;i<16;++i){ aU[i]=0.f; aV[i]=0.f; }
      #pragma unroll 4
      for (int c2=0;c2<12;++c2){
        float xv = v[c2];
        #pragma unroll
        for (int i=0;i<16;++i){
          aU[i] = fmaf(Wd[ob4*16+i][c2], xv, aU[i]);
          aV[i] = fmaf(Wf[ob4*16+i][c2], xv, aV[i]);
        }
      }
      #pragma unroll
      for (int i=0;i<16;++i){
        int o = ob4*16 + i;
        float tt = t1s[o];
        Ut[(size_t)n*64 + o]  = aU[i]*tt;
        Vtb[(size_t)n*64 + o] = fmaf(aV[i] - m1s[o], tt, b1s[o]);
      }
    }
    return;
  }
  b -= nb0;
  if (b < 768){
    int i = b*256 + tid;
    int o = i / 192, c = i % 192;
    w6t[(size_t)c*1024 + o] = W6[(size_t)o*192 + c];
    return;
  }
  b -= 768;
  if (b < 384){
    int i = b*256 + tid;
    int o = i / 192, c = i % 192;
    w7xt[(size_t)c*512 + o] = W7[(size_t)o*1216 + 1024 + c];
    return;
  }
  b -= 384;
  {
    int i = b*256 + tid;
    int o = i / 512, c = i % 512;
    w8t[(size_t)c*256 + o] = W8[(size_t)o*512 + c];
  }
}

// ---------------- fused MFMA kNN (r23 config: med3 chain + 3-stage LDS merge) ----------------
template<int C>
__global__ __launch_bounds__(512) void knn_mfma(
    const unsigned short* __restrict__ xh,
    const unsigned short* __restrict__ xx,
    int* __restrict__ idx, int N)
{
  __shared__ unsigned lists[32][16][KNN_K];
  __shared__ unsigned short xxs[8192];
  int tid = threadIdx.x;
  int w = tid >> 6, lane = tid & 63;
  int g = lane >> 4, c = lane & 15;
  int n0 = blockIdx.x * 16;
  int ntiles = N >> 6;

  ((uint4*)xxs)[tid]       = ((const uint4*)xx)[tid];
  ((uint4*)xxs)[tid + 512] = ((const uint4*)xx)[tid + 512];

  half8 bfrag[C/32];
  #pragma unroll
  for (int kc=0; kc<C/32; ++kc)
    bfrag[kc] = *reinterpret_cast<const half8*>(xh + (size_t)(n0 + c)*C + kc*32 + g*8);
  f16 qxx = us2h(xx[n0 + c]);
  __syncthreads();

  unsigned tk[KNN_K];
  #pragma unroll
  for (int j=0;j<KNN_K;++j) tk[j] = 0u;

  const unsigned short* ap = xh + (size_t)(w*64 + c)*C + g*8;
  int ml = w*64 + g*4;

  for (int t = w; t < ntiles; t += 8){
    #pragma unroll
    for (int msub=0; msub<4; ++msub){
      const unsigned short* ap2 = ap + msub*(16*C);
      f32x4 acc = {0.f,0.f,0.f,0.f};
      #pragma unroll
      for (int kc=0; kc<C/32; ++kc){
        half8 af = *reinterpret_cast<const half8*>(ap2 + kc*32);
        acc = __builtin_amdgcn_mfma_f32_16x16x32_f16(af, bfrag[kc], acc, 0, 0, 0);
      }
      #pragma unroll
      for (int j=0;j<4;++j){
        int mloc = ml + msub*16 + j;
        f16 dh = (f16)acc[j];
        f16 mi = dh * (f16)(-2.0f);
        f16 xm = us2h(xxs[mloc]);
        f16 t1 = (-xm) - mi;
        f16 pdh = t1 - qxx;
        insert_nc(tk, pack_key16(pdh, mloc));
      }
    }
    ap += (size_t)512*C;
    ml += 512;
  }

  {
    unsigned* dst = lists[w*4 + g][c];
    #pragma unroll
    for (int j=0;j<KNN_K;++j) dst[j] = tk[j];
  }
  __syncthreads();

  unsigned tk2[KNN_K];
  if (tid < 128){
    int n = tid >> 3, q = tid & 7;
    #pragma unroll
    for (int j=0;j<KNN_K;++j) tk2[j] = lists[q*4][n][j];
    for (int li=1; li<4; ++li) merge_sorted(tk2, lists[q*4 + li][n]);
  }
  __syncthreads();
  if (tid < 128){
    int n = tid >> 3, q = tid & 7;
    unsigned* dst = lists[q][n];
    #pragma unroll
    for (int j=0;j<KNN_K;++j) dst[j] = tk2[j];
  }
  __syncthreads();
  if (tid < 32){
    int n = tid >> 1, h = tid & 1;
    #pragma unroll
    for (int j=0;j<KNN_K;++j) tk2[j] = lists[h*4][n][j];
    for (int li=1; li<4; ++li) merge_sorted(tk2, lists[h*4 + li][n]);
  }
  __syncthreads();
  if (tid < 32){
    int n = tid >> 1, h = tid & 1;
    unsigned* dst = lists[h][n];
    #pragma unroll
    for (int j=0;j<KNN_K;++j) dst[j] = tk2[j];
  }
  __syncthreads();
  if (tid < 16){
    int n = tid;
    #pragma unroll
    for (int j=0;j<KNN_K;++j) tk2[j] = lists[0][n][j];
    merge_sorted(tk2, lists[1][n]);
    #pragma unroll
    for (int j=0;j<KNN_K;++j)
      idx[(size_t)(n0 + n)*KNN_K + j] = (int)((~tk2[j]) & 0xFFFFu);
  }
}

// ---------------- edge conv v5: 4 q's per wave ----------------
template<bool SECOND>
__global__ __launch_bounds__(256) void edge2(
    const float* __restrict__ Ut, const float* __restrict__ Vtb,
    const int* __restrict__ idx,
    const float* __restrict__ W2, const float* __restrict__ bn2,
    float* __restrict__ outCN, unsigned short* __restrict__ outh,
    unsigned short* __restrict__ outxx, int N,
    const float* __restrict__ Wn, const float* __restrict__ bnn,
    float* __restrict__ UtN, float* __restrict__ VtbN)
{
  __shared__ float eb[4][4][64];
  __shared__ float xb[16][64];
  int w = threadIdx.x >> 6, o = threadIdx.x & 63;
  float w2r[64]; float t2=0.f,b2=0.f,m2=0.f;
  if (SECOND){
    #pragma unroll
    for (int c4=0;c4<16;++c4){
      float4 wv = *reinterpret_cast<const float4*>(W2 + (size_t)o*64 + c4*4);
      w2r[c4*4+0]=wv.x; w2r[c4*4+1]=wv.y; w2r[c4*4+2]=wv.z; w2r[c4*4+3]=wv.w;
    }
    t2 = bn2[o]/sqrtf(bn2[192+o]+1e-5f); b2 = bn2[64+o]; m2 = bn2[128+o];
  }
  int nq = blockIdx.x*16 + w*4;
  float vo[4], u[4], best[4];
  const int* ip[4];
  int jj[4];
  #pragma unroll
  for (int q=0;q<4;++q){
    vo[q] = Vtb[(size_t)(nq+q)*64 + o];
    ip[q] = idx + (size_t)(nq+q)*KNN_K;
    jj[q] = ip[q][0];
    u[q]  = Ut[(size_t)jj[q]*64 + o];
    best[q] = -INFINITY;
  }
  #pragma unroll 1
  for (int k=0;k<KNN_K;++k){
    float uc[4];
    #pragma unroll
    for (int q=0;q<4;++q) uc[q] = u[q];
    if (k < KNN_K-1){
      #pragma unroll
      for (int q=0;q<4;++q){ jj[q] = ip[q][k+1]; u[q] = Ut[(size_t)jj[q]*64 + o]; }
    }
    float e[4];
    #pragma unroll
    for (int q=0;q<4;++q) e[q] = lrelu(uc[q] + vo[q]);
    if (SECOND){
      #pragma unroll
      for (int q=0;q<4;++q) eb[q][w][o] = e[q];
      float s0[4], s1[4], s2[4], s3[4];
      #pragma unroll
      for (int q=0;q<4;++q){ s0[q]=0.f; s1[q]=0.f; s2[q]=0.f; s3[q]=0.f; }
      #pragma unroll
      for (int c4=0;c4<16;++c4){
        #pragma unroll
        for (int q=0;q<4;++q){
          float4 ev = *reinterpret_cast<const float4*>(eb[q][w] + c4*4);
          s0[q] = fmaf(w2r[c4*4+0], ev.x, s0[q]);
          s1[q] = fmaf(w2r[c4*4+1], ev.y, s1[q]);
          s2[q] = fmaf(w2r[c4*4+2], ev.z, s2[q]);
          s3[q] = fmaf(w2r[c4*4+3], ev.w, s3[q]);
        }
      }
      #pragma unroll
      for (int q=0;q<4;++q){
        float s = (s0[q]+s1[q])+(s2[q]+s3[q]);
        best[q] = fmaxf(best[q], lrelu(fmaf(s - m2, t2, b2)));
      }
    } else {
      #pragma unroll
      for (int q=0;q<4;++q) best[q] = fmaxf(best[q], e[q]);
    }
  }
  #pragma unroll
  for (int q=0;q<4;++q) outCN[(size_t)o*N + nq + q] = best[q];
  if (SECOND){
    float p[4];
    #pragma unroll
    for (int q=0;q<4;++q){
      f16 h = (f16)best[q]; float hf = (float)h;
      outh[(size_t)(nq+q)*64 + o] = h2us(h);
      p[q] = (float)(f16)(hf*hf);
    }
    #pragma unroll
    for (int s2s=32;s2s>=1;s2s>>=1){
      #pragma unroll
      for (int q=0;q<4;++q) p[q] += __shfl_xor(p[q], s2s, 64);
    }
    if (o == 0){
      #pragma unroll
      for (int q=0;q<4;++q) outxx[nq+q] = h2us((f16)p[q]);
    }
    if (Wn){
      #pragma unroll
      for (int q=0;q<4;++q) xb[w*4+q][o] = best[q];
      float tn = bnn[o]/sqrtf(bnn[192+o]+1e-5f);
      float bb = bnn[64+o], mm = bnn[128+o];
      const float* wr = Wn + (size_t)o*128;
      float aU[4], aV[4];
      #pragma unroll
      for (int q=0;q<4;++q){ aU[q]=0.f; aV[q]=0.f; }
      #pragma unroll 8
      for (int c=0;c<64;++c){
        float wd = wr[c], wc = wr[64+c];
        float wdf = wc - wd;
        #pragma unroll
        for (int q=0;q<4;++q){
          float xv = xb[w*4+q][c];
          aU[q] = fmaf(wd, xv, aU[q]);
          aV[q] = fmaf(wdf, xv, aV[q]);
        }
      }
      #pragma unroll
      for (int q=0;q<4;++q){
        UtN[(size_t)(nq+q)*64 + o]  = aU[q]*tn;
        VtbN[(size_t)(nq+q)*64 + o] = fmaf(aV[q] - mm, tn, bb);
      }
    }
  }
}

// ---------------- conv67: conv6 (bn6+lrelu+gmax) and conv7-raw merged ----------------
__global__ __launch_bounds__(256) void conv67(
    const float* __restrict__ w6t, const float* __restrict__ w7xt,
    const float* __restrict__ sA, const float* __restrict__ sB, const float* __restrict__ sC,
    const float* __restrict__ bn6,
    float* __restrict__ gpart, float* __restrict__ h7raw, int N)
{
  __shared__ float ws[2][32][68];
  int tid = threadIdx.x;
  int ln = tid & 63;
  int og = (tid >> 6) * 16;
  int n0 = blockIdx.x*128;
  int y = blockIdx.y;
  bool six = (y < 16);
  int O  = six ? 1024 : 512;
  int ob = six ? y*64 : (y-16)*64;
  const float* WT = six ? w6t : w7xt;
  int n = n0 + ln*2;
  float a0[16], a1[16];
  #pragma unroll
  for (int i=0;i<16;++i){ a0[i]=0.f; a1[i]=0.f; }

  auto stage = [&](int m, int buf){
    int c0 = m*32;
    #pragma unroll
    for (int r=0;r<8;++r){
      int i = r*256 + tid;
      int cc = i >> 6, oo = i & 63;
      ws[buf][cc][oo] = WT[(size_t)(c0+cc)*O + ob + oo];
    }
  };
  auto srcrow = [&](int crow)->const float*{
    if (crow < 64) return sA + (size_t)crow*N;
    crow -= 64;
    if (crow < 64) return sB + (size_t)crow*N;
    crow -= 64;
    return sC + (size_t)crow*N;
  };

  stage(0, 0);
  __syncthreads();
  #pragma unroll 1
  for (int m=0; m<6; ++m){
    int buf = m & 1;
    if (m+1 < 6) stage(m+1, buf^1);
    const float* srow = srcrow(m*32);
    #pragma unroll 4
    for (int cc=0; cc<32; ++cc){
      float2 xv = *reinterpret_cast<const float2*>(srow + (size_t)cc*N + n);
      const float* wr = &ws[buf][cc][og];
      #pragma unroll
      for (int i=0;i<16;++i){
        a0[i] = fmaf(wr[i], xv.x, a0[i]);
        a1[i] = fmaf(wr[i], xv.y, a1[i]);
      }
    }
    __syncthreads();
  }
  if (six){
    #pragma unroll
    for (int i=0;i<16;++i){
      int oG = ob + og + i;
      float t = bn6[oG] / sqrtf(bn6[3*1024+oG] + 1e-5f);
      float mm = bn6[2*1024+oG], bb = bn6[1*1024+oG];
      a0[i] = lrelu(fmaf(a0[i] - mm, t, bb));
      a1[i] = lrelu(fmaf(a1[i] - mm, t, bb));
      float v = fmaxf(a0[i], a1[i]);
      #pragma unroll
      for (int s=32;s>=1;s>>=1) v = fmaxf(v, __shfl_xor(v, s, 64));
      if (ln == 0) gpart[(size_t)oG*gridDim.x + blockIdx.x] = v;
    }
  } else {
    #pragma unroll
    for (int i=0;i<16;++i){
      float2 st = {a0[i], a1[i]};
      *reinterpret_cast<float2*>(h7raw + (size_t)(ob+og+i)*N + n) = st;
    }
  }
}

// ---------------- fused global-max + W7 g-bias ----------------
__global__ __launch_bounds__(1024) void gmax_bias7(
    const float* __restrict__ gpart, const float* __restrict__ W7,
    float* __restrict__ b7, int P)
{
  __shared__ float gs[1024];
  int t = threadIdx.x;
  float m = -INFINITY;
  for (int p=0;p<P;++p) m = fmaxf(m, gpart[(size_t)t*P + p]);
  gs[t] = m;
  __syncthreads();
  int w = t >> 6, ln = t & 63;
  #pragma unroll 1
  for (int oi=0; oi<32; ++oi){
    int o = w*32 + oi;
    float a = 0.f;
    #pragma unroll
    for (int c0=0; c0<1024; c0+=64)
      a = fmaf(W7[(size_t)o*1216 + c0 + ln], gs[c0 + ln], a);
    #pragma unroll
    for (int s=32;s>=1;s>>=1) a += __shfl_xor(a, s, 64);
    if (ln == 0) b7[o] = a;
  }
}

// ---------------- conv8 v2: o-tile 32 x n-tile 128, y-grid 8 ----------------
__global__ __launch_bounds__(256) void conv8w(
    const float* __restrict__ w8t,
    const float* __restrict__ h7raw,
    const float* __restrict__ b7, const float* __restrict__ bn7,
    const float* __restrict__ bn8,
    float* __restrict__ h8, int N)
{
  __shared__ float ws[2][32][36];
  __shared__ float e7s[512], t7s[512], mm7s[512], bb7s[512];
  int tid = threadIdx.x;
  int ln = tid & 63;
  int og = (tid >> 6) * 8;
  int n0 = blockIdx.x*128;
  int ob = blockIdx.y*32;
  int n = n0 + ln*2;
  for (int c = tid; c < 512; c += 256){
    t7s[c]  = bn7[c] / sqrtf(bn7[3*512+c] + 1e-5f);
    bb7s[c] = bn7[512+c];
    mm7s[c] = bn7[2*512+c];
    e7s[c]  = b7[c];
  }
  float a0[8], a1[8];
  #pragma unroll
  for (int i=0;i<8;++i){ a0[i]=0.f; a1[i]=0.f; }

  auto stage = [&](int m, int buf){
    int c0 = m*32;
    #pragma unroll
    for (int r=0;r<4;++r){
      int i = r*256 + tid;
      int cc = i >> 5, oo = i & 31;
      ws[buf][cc][oo] = w8t[(size_t)(c0+cc)*256 + ob + oo];
    }
  };

  stage(0, 0);
  __syncthreads();
  #pragma unroll 1
  for (int m=0; m<16; ++m){
    int buf = m & 1;
    if (m+1 < 16) stage(m+1, buf^1);
    int c0 = m*32;
    #pragma unroll 4
    for (int cc=0; cc<32; ++cc){
      int c = c0 + cc;
      float2 raw = *reinterpret_cast<const float2*>(h7raw + (size_t)c*N + n);
      float e = e7s[c], mm = mm7s[c], t = t7s[c], bb = bb7s[c];
      float xv0 = lrelu(fmaf((raw.x + e) - mm, t, bb));
      float xv1 = lrelu(fmaf((raw.y + e) - mm, t, bb));
      const float* wr = &ws[buf][cc][og];
      #pragma unroll
      for (int i=0;i<8;++i){
        a0[i] = fmaf(wr[i], xv0, a0[i]);
        a1[i] = fmaf(wr[i], xv1, a1[i]);
      }
    }
    __syncthreads();
  }
  #pragma unroll
  for (int i=0;i<8;++i){
    int oG = ob + og + i;
    float t = bn8[oG] / sqrtf(bn8[3*256+oG] + 1e-5f);
    float mm = bn8[2*256+oG], bb = bn8[256+oG];
    a0[i] = lrelu(fmaf(a0[i] - mm, t, bb));
    a1[i] = lrelu(fmaf(a1[i] - mm, t, bb));
    float2 st = {a0[i], a1[i]};
    *reinterpret_cast<float2*>(h8 + (size_t)oG*N + n) = st;
  }
}

__global__ __launch_bounds__(256) void w9_kernel(
    const float* __restrict__ W9, const float* __restrict__ h8, float* __restrict__ out, int N)
{
  int n = blockIdx.x*256 + threadIdx.x;
  if (n >= N) return;
  float a0=0.f, a1=0.f, a2=0.f;
  for (int c=0;c<256;++c){
    float xv = h8[(size_t)c*N + n];
    a0 = fmaf(W9[c],       xv, a0);
    a1 = fmaf(W9[256+c],   xv, a1);
    a2 = fmaf(W9[512+c],   xv, a2);
  }
  out[(size_t)n*3+0]=a0; out[(size_t)n*3+1]=a1; out[(size_t)n*3+2]=a2;
}

extern "C" void kernel_launch(void* const* d_in, const int* in_sizes, int n_in,
                              void* d_out, int out_size, void* d_ws, size_t ws_size,
                              hipStream_t stream) {
  const float* curr_pos = (const float*)d_in[0];
  const int*   node_t   = (const int*)  d_in[1];
  const float* W1 = (const float*)d_in[2];
  const float* W2 = (const float*)d_in[3];
  const float* W3 = (const float*)d_in[4];
  const float* W4 = (const float*)d_in[5];
  const float* W5 = (const float*)d_in[6];
  const float* W6 = (const float*)d_in[7];
  const float* W7 = (const float*)d_in[8];
  const float* W8 = (const float*)d_in[9];
  const float* W9 = (const float*)d_in[10];
  const float* bn1 = (const float*)d_in[11];
  const float* bn2 = (const float*)d_in[12];
  const float* bn3 = (const float*)d_in[13];
  const float* bn4 = (const float*)d_in[14];
  const float* bn5 = (const float*)d_in[15];
  const float* bn6 = (const float*)d_in[16];
  const float* bn7 = (const float*)d_in[17];
  const float* bn8 = (const float*)d_in[18];
  float* out = (float*)d_out;

  const int N = in_sizes[0] / 3;

  char* ws = (char*)d_ws;
  size_t off = 0;
  auto A = [&](size_t b){ size_t o = off; off = (o + b + 255) & ~(size_t)255; return o; };

  unsigned short* xh0 = (unsigned short*)(ws + A((size_t)N*32*2));
  unsigned short* xx0 = (unsigned short*)(ws + A((size_t)N*2));
  float* x1CN = (float*)(ws + A((size_t)N*64*4));
  unsigned short* xh1 = (unsigned short*)(ws + A((size_t)N*64*2));
  unsigned short* xx1 = (unsigned short*)(ws + A((size_t)N*2));
  float* x2CN = (float*)(ws + A((size_t)N*64*4));
  unsigned short* xh2 = (unsigned short*)(ws + A((size_t)N*64*2));
  unsigned short* xx2 = (unsigned short*)(ws + A((size_t)N*2));
  float* x3CN = (float*)(ws + A((size_t)N*64*4));
  int* idxb = (int*)(ws + A((size_t)N*KNN_K*4));
  float* Ut  = (float*)(ws + A((size_t)N*64*4));
  float* Vtb = (float*)(ws + A((size_t)N*64*4));
  float* Ut2  = (float*)(ws + A((size_t)N*64*4));
  float* Vtb2 = (float*)(ws + A((size_t)N*64*4));
  float* w6t  = (float*)(ws + A((size_t)192*1024*4));
  float* w7xt = (float*)(ws + A((size_t)192*512*4));
  float* w8t  = (float*)(ws + A((size_t)512*256*4));
  float* gpart= (float*)(ws + A((size_t)1024*(N/64)*4));
  float* b7   = (float*)(ws + A((size_t)512*4));
  float* h7raw= (float*)(ws + A((size_t)512*N*4));
  float* h8   = (float*)(ws + A((size_t)256*N*4));
  if (off > ws_size) return;

  dim3 b256(256), b512(512);
  int nb0 = (N + 255) / 256;
  prep0<<<dim3(nb0 + 768 + 384 + 512), b256, 0, stream>>>(
      curr_pos, node_t, xh0, xx0, N, W1, bn1, Ut, Vtb, W6, w6t, W7, w7xt, W8, w8t);

  dim3 gknn(N/16);
  dim3 gec(N/16);
  dim3 gfin((N+255)/256);

  // round 1  (edge2 epilogue computes UV for round 2 from x1/W3/bn3)
  knn_mfma<32><<<gknn, b512, 0, stream>>>(xh0, xx0, idxb, N);
  edge2<true><<<gec, b256, 0, stream>>>(Ut, Vtb, idxb, W2, bn2, x1CN, xh1, xx1, N, W3, bn3, Ut2, Vtb2);
  // round 2
  knn_mfma<64><<<gknn, b512, 0, stream>>>(xh1, xx1, idxb, N);
  edge2<true><<<gec, b256, 0, stream>>>(Ut2, Vtb2, idxb, W4, bn4, x2CN, xh2, xx2, N, W5, bn5, Ut, Vtb);
  // round 3
  knn_mfma<64><<<gknn, b512, 0, stream>>>(xh2, xx2, idxb, N);
  edge2<false><<<gec, b256, 0, stream>>>(Ut, Vtb, idxb, nullptr, nullptr, x3CN, nullptr, nullptr, N, nullptr, nullptr, nullptr, nullptr);
  // head
  conv67<<<dim3(N/128, 24), b256, 0, stream>>>(w6t, w7xt, x1CN, x2CN, x3CN, bn6, gpart, h7raw, N);
  gmax_bias7<<<dim3(1), dim3(1024), 0, stream>>>(gpart, W7, b7, N/128);
  conv8w<<<dim3(N/128, 8), b256, 0, stream>>>(w8t, h7raw, b7, bn7, bn8, h8, N);
  w9_kernel<<<gfin, b256, 0, stream>>>(W9, h8, out, N);
}

// Round 26
// 538.237 us; speedup vs baseline: 1.0340x; 1.0067x over previous
//
#include <hip/hip_runtime.h>
#include <hip/hip_bf16.h>

#define KNN_K 20
typedef _Float16 f16;
typedef _Float16 half8 __attribute__((ext_vector_type(8)));
typedef float f32x4 __attribute__((ext_vector_type(4)));

__device__ __forceinline__ float lrelu(float x){ return x >= 0.f ? x : 0.2f*x; }
__device__ __forceinline__ f16 us2h(unsigned short u){ union{unsigned short u; f16 h;} x; x.u=u; return x.h; }
__device__ __forceinline__ unsigned short h2us(f16 h){ union{unsigned short u; f16 h;} x; x.h=h; return x.u; }

__device__ __forceinline__ unsigned pack_key16(f16 v, int m){
  unsigned u = h2us(v);
  unsigned s = (u & 0x8000u) ? ((~u) & 0xFFFFu) : (u | 0x8000u);
  return (s << 16) | ((~(unsigned)m) & 0xFFFFu);
}

__device__ __forceinline__ unsigned med3u(unsigned a, unsigned b, unsigned c){
  unsigned d;
  asm("v_med3_u32 %0, %1, %2, %3" : "=v"(d) : "v"(a), "v"(b), "v"(c));
  return d;
}

// Sorted-desc insert via median: tk'[j] = med3(tk[j-1], tk[j], key), reverse order
// (reads see OLD values; depth-1 dependencies; 20 ops). Exact.
__device__ __forceinline__ void insert_nc(unsigned* tk, unsigned key){
  #pragma unroll
  for (int j=KNN_K-1; j>=1; --j)
    tk[j] = med3u(tk[j-1], tk[j], key);
  tk[0] = max(tk[0], key);
}

__device__ __forceinline__ void merge_sorted(unsigned* tk, const unsigned* src){
  #pragma unroll
  for (int j=0;j<KNN_K;++j){
    unsigned key = src[j];
    if (key <= tk[KNN_K-1]) break;
    insert_nc(tk, key);
  }
}

// ---------------- prep0: x0 build + round-1 UV (fused) + all weight transposes ----------------
__global__ __launch_bounds__(256) void prep0(
    const float* __restrict__ pos, const int* __restrict__ nt,
    unsigned short* __restrict__ xh0, unsigned short* __restrict__ xx0, int N,
    const float* __restrict__ W1, const float* __restrict__ bn1,
    float* __restrict__ Ut, float* __restrict__ Vtb,
    const float* __restrict__ W6, float* __restrict__ w6t,
    const float* __restrict__ W7, float* __restrict__ w7xt,
    const float* __restrict__ W8, float* __restrict__ w8t)
{
  __shared__ float Wd[64][12], Wf[64][12];
  __shared__ float t1s[64], b1s[64], m1s[64];
  int b = blockIdx.x, tid = threadIdx.x;
  int nb0 = (N + 255) >> 8;
  if (b < nb0){
    for (int i = tid; i < 768; i += 256){
      int o = i / 12, c = i % 12;
      float wd = W1[(size_t)o*24 + c];
      Wd[o][c] = wd;
      Wf[o][c] = W1[(size_t)o*24 + 12 + c] - wd;
    }
    if (tid < 64){
      t1s[tid] = bn1[tid] / sqrtf(bn1[192+tid] + 1e-5f);
      b1s[tid] = bn1[64+tid];
      m1s[tid] = bn1[128+tid];
    }
    __syncthreads();
    int n = b*256 + tid;
    float v[12];
    v[0]=pos[n*3+0]; v[1]=pos[n*3+1]; v[2]=pos[n*3+2];
    int t = nt[n];
    #pragma unroll
    for (int c=0;c<9;++c) v[3+c] = (t==c) ? 1.f : 0.f;
    float xa = 0.f;
    #pragma unroll
    for (int c=0;c<12;++c){
      f16 h = (f16)v[c];
      float hf = (float)h;
      xh0[(size_t)n*32+c] = h2us(h);
      f16 pe = (f16)(hf*hf);
      xa += (float)pe;
    }
    #pragma unroll
    for (int c=12;c<32;++c) xh0[(size_t)n*32+c] = 0;
    xx0[n] = h2us((f16)xa);
    #pragma unroll 1
    for (int ob4=0; ob4<4; ++ob4){
      float aU[16], aV[16];
      #pragma unroll
      for (int i=0;i<16;++i){ aU[i]=0.f; aV[i]=0.f; }
      #pragma unroll 4
      for (int c2=0;c2<12;++c2){
        float xv = v[c2];
        #pragma unroll
        for (int i=0;i<16;++i){
          aU[i] = fmaf(Wd[ob4*16+i][c2], xv, aU[i]);
          aV[i] = fmaf(Wf[ob4*16+i][c2], xv, aV[i]);
        }
      }
      #pragma unroll
      for (int i=0;i<16;++i){
        int o = ob4*16 + i;
        float tt = t1s[o];
        Ut[(size_t)n*64 + o]  = aU[i]*tt;
        Vtb[(size_t)n*64 + o] = fmaf(aV[i] - m1s[o], tt, b1s[o]);
      }
    }
    return;
  }
  b -= nb0;
  if (b < 768){
    int i = b*256 + tid;
    int o = i / 192, c = i % 192;
    w6t[(size_t)c*1024 + o] = W6[(size_t)o*192 + c];
    return;
  }
  b -= 768;
  if (b < 384){
    int i = b*256 + tid;
    int o = i / 192, c = i % 192;
    w7xt[(size_t)c*512 + o] = W7[(size_t)o*1216 + 1024 + c];
    return;
  }
  b -= 384;
  {
    int i = b*256 + tid;
    int o = i / 512, c = i % 512;
    w8t[(size_t)c*256 + o] = W8[(size_t)o*512 + c];
  }
}

// ---------------- fused MFMA kNN: med3 chain + 3-stage LDS merge + SW-pipelined af loads ----------------
template<int C>
__global__ __launch_bounds__(512) void knn_mfma(
    const unsigned short* __restrict__ xh,
    const unsigned short* __restrict__ xx,
    int* __restrict__ idx, int N)
{
  constexpr int KC = C/32;
  __shared__ unsigned lists[32][16][KNN_K];
  __shared__ unsigned short xxs[8192];
  int tid = threadIdx.x;
  int w = tid >> 6, lane = tid & 63;
  int g = lane >> 4, c = lane & 15;
  int n0 = blockIdx.x * 16;
  int ntiles = N >> 6;

  ((uint4*)xxs)[tid]       = ((const uint4*)xx)[tid];
  ((uint4*)xxs)[tid + 512] = ((const uint4*)xx)[tid + 512];

  half8 bfrag[KC];
  #pragma unroll
  for (int kc=0; kc<KC; ++kc)
    bfrag[kc] = *reinterpret_cast<const half8*>(xh + (size_t)(n0 + c)*C + kc*32 + g*8);
  f16 qxx = us2h(xx[n0 + c]);
  __syncthreads();

  unsigned tk[KNN_K];
  #pragma unroll
  for (int j=0;j<KNN_K;++j) tk[j] = 0u;

  const unsigned short* ap = xh + (size_t)(w*64 + c)*C + g*8;
  int ml = w*64 + g*4;

  // preload iteration t = w
  half8 afr[4*KC];
  #pragma unroll
  for (int msub=0; msub<4; ++msub)
    #pragma unroll
    for (int kc=0; kc<KC; ++kc)
      afr[msub*KC+kc] = *reinterpret_cast<const half8*>(ap + msub*(16*C) + kc*32);

  for (int t = w; t < ntiles; t += 8){
    half8 afn[4*KC];
    bool more = (t + 8) < ntiles;
    if (more){
      const unsigned short* basen = ap + (size_t)512*C;
      #pragma unroll
      for (int msub=0; msub<4; ++msub)
        #pragma unroll
        for (int kc=0; kc<KC; ++kc)
          afn[msub*KC+kc] = *reinterpret_cast<const half8*>(basen + msub*(16*C) + kc*32);
    }
    #pragma unroll
    for (int msub=0; msub<4; ++msub){
      f32x4 acc = {0.f,0.f,0.f,0.f};
      #pragma unroll
      for (int kc=0; kc<KC; ++kc)
        acc = __builtin_amdgcn_mfma_f32_16x16x32_f16(afr[msub*KC+kc], bfrag[kc], acc, 0, 0, 0);
      #pragma unroll
      for (int j=0;j<4;++j){
        int mloc = ml + msub*16 + j;
        f16 dh = (f16)acc[j];
        f16 mi = dh * (f16)(-2.0f);
        f16 xm = us2h(xxs[mloc]);
        f16 t1 = (-xm) - mi;
        f16 pdh = t1 - qxx;
        insert_nc(tk, pack_key16(pdh, mloc));
      }
    }
    if (more){
      #pragma unroll
      for (int i=0;i<4*KC;++i) afr[i] = afn[i];
    }
    ap += (size_t)512*C;
    ml += 512;
  }

  {
    unsigned* dst = lists[w*4 + g][c];
    #pragma unroll
    for (int j=0;j<KNN_K;++j) dst[j] = tk[j];
  }
  __syncthreads();

  unsigned tk2[KNN_K];
  if (tid < 128){
    int n = tid >> 3, q = tid & 7;
    #pragma unroll
    for (int j=0;j<KNN_K;++j) tk2[j] = lists[q*4][n][j];
    for (int li=1; li<4; ++li) merge_sorted(tk2, lists[q*4 + li][n]);
  }
  __syncthreads();
  if (tid < 128){
    int n = tid >> 3, q = tid & 7;
    unsigned* dst = lists[q][n];
    #pragma unroll
    for (int j=0;j<KNN_K;++j) dst[j] = tk2[j];
  }
  __syncthreads();
  if (tid < 32){
    int n = tid >> 1, h = tid & 1;
    #pragma unroll
    for (int j=0;j<KNN_K;++j) tk2[j] = lists[h*4][n][j];
    for (int li=1; li<4; ++li) merge_sorted(tk2, lists[h*4 + li][n]);
  }
  __syncthreads();
  if (tid < 32){
    int n = tid >> 1, h = tid & 1;
    unsigned* dst = lists[h][n];
    #pragma unroll
    for (int j=0;j<KNN_K;++j) dst[j] = tk2[j];
  }
  __syncthreads();
  if (tid < 16){
    int n = tid;
    #pragma unroll
    for (int j=0;j<KNN_K;++j) tk2[j] = lists[0][n][j];
    merge_sorted(tk2, lists[1][n]);
    #pragma unroll
    for (int j=0;j<KNN_K;++j)
      idx[(size_t)(n0 + n)*KNN_K + j] = (int)((~tk2[j]) & 0xFFFFu);
  }
}

// ---------------- edge conv v5: 4 q's per wave ----------------
template<bool SECOND>
__global__ __launch_bounds__(256) void edge2(
    const float* __restrict__ Ut, const float* __restrict__ Vtb,
    const int* __restrict__ idx,
    const float* __restrict__ W2, const float* __restrict__ bn2,
    float* __restrict__ outCN, unsigned short* __restrict__ outh,
    unsigned short* __restrict__ outxx, int N,
    const float* __restrict__ Wn, const float* __restrict__ bnn,
    float* __restrict__ UtN, float* __restrict__ VtbN)
{
  __shared__ float eb[4][4][64];
  __shared__ float xb[16][64];
  int w = threadIdx.x >> 6, o = threadIdx.x & 63;
  float w2r[64]; float t2=0.f,b2=0.f,m2=0.f;
  if (SECOND){
    #pragma unroll
    for (int c4=0;c4<16;++c4){
      float4 wv = *reinterpret_cast<const float4*>(W2 + (size_t)o*64 + c4*4);
      w2r[c4*4+0]=wv.x; w2r[c4*4+1]=wv.y; w2r[c4*4+2]=wv.z; w2r[c4*4+3]=wv.w;
    }
    t2 = bn2[o]/sqrtf(bn2[192+o]+1e-5f); b2 = bn2[64+o]; m2 = bn2[128+o];
  }
  int nq = blockIdx.x*16 + w*4;
  float vo[4], u[4], best[4];
  const int* ip[4];
  int jj[4];
  #pragma unroll
  for (int q=0;q<4;++q){
    vo[q] = Vtb[(size_t)(nq+q)*64 + o];
    ip[q] = idx + (size_t)(nq+q)*KNN_K;
    jj[q] = ip[q][0];
    u[q]  = Ut[(size_t)jj[q]*64 + o];
    best[q] = -INFINITY;
  }
  #pragma unroll 1
  for (int k=0;k<KNN_K;++k){
    float uc[4];
    #pragma unroll
    for (int q=0;q<4;++q) uc[q] = u[q];
    if (k < KNN_K-1){
      #pragma unroll
      for (int q=0;q<4;++q){ jj[q] = ip[q][k+1]; u[q] = Ut[(size_t)jj[q]*64 + o]; }
    }
    float e[4];
    #pragma unroll
    for (int q=0;q<4;++q) e[q] = lrelu(uc[q] + vo[q]);
    if (SECOND){
      #pragma unroll
      for (int q=0;q<4;++q) eb[q][w][o] = e[q];
      float s0[4], s1[4], s2[4], s3[4];
      #pragma unroll
      for (int q=0;q<4;++q){ s0[q]=0.f; s1[q]=0.f; s2[q]=0.f; s3[q]=0.f; }
      #pragma unroll
      for (int c4=0;c4<16;++c4){
        #pragma unroll
        for (int q=0;q<4;++q){
          float4 ev = *reinterpret_cast<const float4*>(eb[q][w] + c4*4);
          s0[q] = fmaf(w2r[c4*4+0], ev.x, s0[q]);
          s1[q] = fmaf(w2r[c4*4+1], ev.y, s1[q]);
          s2[q] = fmaf(w2r[c4*4+2], ev.z, s2[q]);
          s3[q] = fmaf(w2r[c4*4+3], ev.w, s3[q]);
        }
      }
      #pragma unroll
      for (int q=0;q<4;++q){
        float s = (s0[q]+s1[q])+(s2[q]+s3[q]);
        best[q] = fmaxf(best[q], lrelu(fmaf(s - m2, t2, b2)));
      }
    } else {
      #pragma unroll
      for (int q=0;q<4;++q) best[q] = fmaxf(best[q], e[q]);
    }
  }
  #pragma unroll
  for (int q=0;q<4;++q) outCN[(size_t)o*N + nq + q] = best[q];
  if (SECOND){
    float p[4];
    #pragma unroll
    for (int q=0;q<4;++q){
      f16 h = (f16)best[q]; float hf = (float)h;
      outh[(size_t)(nq+q)*64 + o] = h2us(h);
      p[q] = (float)(f16)(hf*hf);
    }
    #pragma unroll
    for (int s2s=32;s2s>=1;s2s>>=1){
      #pragma unroll
      for (int q=0;q<4;++q) p[q] += __shfl_xor(p[q], s2s, 64);
    }
    if (o == 0){
      #pragma unroll
      for (int q=0;q<4;++q) outxx[nq+q] = h2us((f16)p[q]);
    }
    if (Wn){
      #pragma unroll
      for (int q=0;q<4;++q) xb[w*4+q][o] = best[q];
      float tn = bnn[o]/sqrtf(bnn[192+o]+1e-5f);
      float bb = bnn[64+o], mm = bnn[128+o];
      const float* wr = Wn + (size_t)o*128;
      float aU[4], aV[4];
      #pragma unroll
      for (int q=0;q<4;++q){ aU[q]=0.f; aV[q]=0.f; }
      #pragma unroll 8
      for (int c=0;c<64;++c){
        float wd = wr[c], wc = wr[64+c];
        float wdf = wc - wd;
        #pragma unroll
        for (int q=0;q<4;++q){
          float xv = xb[w*4+q][c];
          aU[q] = fmaf(wd, xv, aU[q]);
          aV[q] = fmaf(wdf, xv, aV[q]);
        }
      }
      #pragma unroll
      for (int q=0;q<4;++q){
        UtN[(size_t)(nq+q)*64 + o]  = aU[q]*tn;
        VtbN[(size_t)(nq+q)*64 + o] = fmaf(aV[q] - mm, tn, bb);
      }
    }
  }
}

// ---------------- conv67: conv6 (bn6+lrelu+gmax) and conv7-raw merged ----------------
__global__ __launch_bounds__(256) void conv67(
    const float* __restrict__ w6t, const float* __restrict__ w7xt,
    const float* __restrict__ sA, const float* __restrict__ sB, const float* __restrict__ sC,
    const float* __restrict__ bn6,
    float* __restrict__ gpart, float* __restrict__ h7raw, int N)
{
  __shared__ float ws[2][32][68];
  int tid = threadIdx.x;
  int ln = tid & 63;
  int og = (tid >> 6) * 16;
  int n0 = blockIdx.x*128;
  int y = blockIdx.y;
  bool six = (y < 16);
  int O  = six ? 1024 : 512;
  int ob = six ? y*64 : (y-16)*64;
  const float* WT = six ? w6t : w7xt;
  int n = n0 + ln*2;
  float a0[16], a1[16];
  #pragma unroll
  for (int i=0;i<16;++i){ a0[i]=0.f; a1[i]=0.f; }

  auto stage = [&](int m, int buf){
    int c0 = m*32;
    #pragma unroll
    for (int r=0;r<8;++r){
      int i = r*256 + tid;
      int cc = i >> 6, oo = i & 63;
      ws[buf][cc][oo] = WT[(size_t)(c0+cc)*O + ob + oo];
    }
  };
  auto srcrow = [&](int crow)->const float*{
    if (crow < 64) return sA + (size_t)crow*N;
    crow -= 64;
    if (crow < 64) return sB + (size_t)crow*N;
    crow -= 64;
    return sC + (size_t)crow*N;
  };

  stage(0, 0);
  __syncthreads();
  #pragma unroll 1
  for (int m=0; m<6; ++m){
    int buf = m & 1;
    if (m+1 < 6) stage(m+1, buf^1);
    const float* srow = srcrow(m*32);
    #pragma unroll 4
    for (int cc=0; cc<32; ++cc){
      float2 xv = *reinterpret_cast<const float2*>(srow + (size_t)cc*N + n);
      const float* wr = &ws[buf][cc][og];
      #pragma unroll
      for (int i=0;i<16;++i){
        a0[i] = fmaf(wr[i], xv.x, a0[i]);
        a1[i] = fmaf(wr[i], xv.y, a1[i]);
      }
    }
    __syncthreads();
  }
  if (six){
    #pragma unroll
    for (int i=0;i<16;++i){
      int oG = ob + og + i;
      float t = bn6[oG] / sqrtf(bn6[3*1024+oG] + 1e-5f);
      float mm = bn6[2*1024+oG], bb = bn6[1*1024+oG];
      a0[i] = lrelu(fmaf(a0[i] - mm, t, bb));
      a1[i] = lrelu(fmaf(a1[i] - mm, t, bb));
      float v = fmaxf(a0[i], a1[i]);
      #pragma unroll
      for (int s=32;s>=1;s>>=1) v = fmaxf(v, __shfl_xor(v, s, 64));
      if (ln == 0) gpart[(size_t)oG*gridDim.x + blockIdx.x] = v;
    }
  } else {
    #pragma unroll
    for (int i=0;i<16;++i){
      float2 st = {a0[i], a1[i]};
      *reinterpret_cast<float2*>(h7raw + (size_t)(ob+og+i)*N + n) = st;
    }
  }
}

// ---------------- gmax + W7 g-bias: 8 blocks, redundant gmax, identical per-o arithmetic ----------------
__global__ __launch_bounds__(1024) void gmax_bias7(
    const float* __restrict__ gpart, const float* __restrict__ W7,
    float* __restrict__ b7, int P)
{
  __shared__ float gs[1024];
  int t = threadIdx.x;
  float m = -INFINITY;
  for (int p=0;p<P;++p) m = fmaxf(m, gpart[(size_t)t*P + p]);
  gs[t] = m;
  __syncthreads();
  int w = t >> 6, ln = t & 63;
  #pragma unroll 1
  for (int oi=0; oi<4; ++oi){
    int o = blockIdx.x*64 + w*4 + oi;
    float a = 0.f;
    #pragma unroll
    for (int c0=0; c0<1024; c0+=64)
      a = fmaf(W7[(size_t)o*1216 + c0 + ln], gs[c0 + ln], a);
    #pragma unroll
    for (int s=32;s>=1;s>>=1) a += __shfl_xor(a, s, 64);
    if (ln == 0) b7[o] = a;
  }
}

// ---------------- conv8 v2: o-tile 32 x n-tile 128, y-grid 8 ----------------
__global__ __launch_bounds__(256) void conv8w(
    const float* __restrict__ w8t,
    const float* __restrict__ h7raw,
    const float* __restrict__ b7, const float* __restrict__ bn7,
    const float* __restrict__ bn8,
    float* __restrict__ h8, int N)
{
  __shared__ float ws[2][32][36];
  __shared__ float e7s[512], t7s[512], mm7s[512], bb7s[512];
  int tid = threadIdx.x;
  int ln = tid & 63;
  int og = (tid >> 6) * 8;
  int n0 = blockIdx.x*128;
  int ob = blockIdx.y*32;
  int n = n0 + ln*2;
  for (int c = tid; c < 512; c += 256){
    t7s[c]  = bn7[c] / sqrtf(bn7[3*512+c] + 1e-5f);
    bb7s[c] = bn7[512+c];
    mm7s[c] = bn7[2*512+c];
    e7s[c]  = b7[c];
  }
  float a0[8], a1[8];
  #pragma unroll
  for (int i=0;i<8;++i){ a0[i]=0.f; a1[i]=0.f; }

  auto stage = [&](int m, int buf){
    int c0 = m*32;
    #pragma unroll
    for (int r=0;r<4;++r){
      int i = r*256 + tid;
      int cc = i >> 5, oo = i & 31;
      ws[buf][cc][oo] = w8t[(size_t)(c0+cc)*256 + ob + oo];
    }
  };

  stage(0, 0);
  __syncthreads();
  #pragma unroll 1
  for (int m=0; m<16; ++m){
    int buf = m & 1;
    if (m+1 < 16) stage(m+1, buf^1);
    int c0 = m*32;
    #pragma unroll 4
    for (int cc=0; cc<32; ++cc){
      int c = c0 + cc;
      float2 raw = *reinterpret_cast<const float2*>(h7raw + (size_t)c*N + n);
      float e = e7s[c], mm = mm7s[c], t = t7s[c], bb = bb7s[c];
      float xv0 = lrelu(fmaf((raw.x + e) - mm, t, bb));
      float xv1 = lrelu(fmaf((raw.y + e) - mm, t, bb));
      const float* wr = &ws[buf][cc][og];
      #pragma unroll
      for (int i=0;i<8;++i){
        a0[i] = fmaf(wr[i], xv0, a0[i]);
        a1[i] = fmaf(wr[i], xv1, a1[i]);
      }
    }
    __syncthreads();
  }
  #pragma unroll
  for (int i=0;i<8;++i){
    int oG = ob + og + i;
    float t = bn8[oG] / sqrtf(bn8[3*256+oG] + 1e-5f);
    float mm = bn8[2*256+oG], bb = bn8[256+oG];
    a0[i] = lrelu(fmaf(a0[i] - mm, t, bb));
    a1[i] = lrelu(fmaf(a1[i] - mm, t, bb));
    float2 st = {a0[i], a1[i]};
    *reinterpret_cast<float2*>(h8 + (size_t)oG*N + n) = st;
  }
}

__global__ __launch_bounds__(256) void w9_kernel(
    const float* __restrict__ W9, const float* __restrict__ h8, float* __restrict__ out, int N)
{
  int n = blockIdx.x*256 + threadIdx.x;
  if (n >= N) return;
  float a0=0.f, a1=0.f, a2=0.f;
  for (int c=0;c<256;++c){
    float xv = h8[(size_t)c*N + n];
    a0 = fmaf(W9[c],       xv, a0);
    a1 = fmaf(W9[256+c],   xv, a1);
    a2 = fmaf(W9[512+c],   xv, a2);
  }
  out[(size_t)n*3+0]=a0; out[(size_t)n*3+1]=a1; out[(size_t)n*3+2]=a2;
}

extern "C" void kernel_launch(void* const* d_in, const int* in_sizes, int n_in,
                              void* d_out, int out_size, void* d_ws, size_t ws_size,
                              hipStream_t stream) {
  const float* curr_pos = (const float*)d_in[0];
  const int*   node_t   = (const int*)  d_in[1];
  const float* W1 = (const float*)d_in[2];
  const float* W2 = (const float*)d_in[3];
  const float* W3 = (const float*)d_in[4];
  const float* W4 = (const float*)d_in[5];
  const float* W5 = (const float*)d_in[6];
  const float* W6 = (const float*)d_in[7];
  const float* W7 = (const float*)d_in[8];
  const float* W8 = (const float*)d_in[9];
  const float* W9 = (const float*)d_in[10];
  const float* bn1 = (const float*)d_in[11];
  const float* bn2 = (const float*)d_in[12];
  const float* bn3 = (const float*)d_in[13];
  const float* bn4 = (const float*)d_in[14];
  const float* bn5 = (const float*)d_in[15];
  const float* bn6 = (const float*)d_in[16];
  const float* bn7 = (const float*)d_in[17];
  const float* bn8 = (const float*)d_in[18];
  float* out = (float*)d_out;

  const int N = in_sizes[0] / 3;

  char* ws = (char*)d_ws;
  size_t off = 0;
  auto A = [&](size_t b){ size_t o = off; off = (o + b + 255) & ~(size_t)255; return o; };

  unsigned short* xh0 = (unsigned short*)(ws + A((size_t)N*32*2));
  unsigned short* xx0 = (unsigned short*)(ws + A((size_t)N*2));
  float* x1CN = (float*)(ws + A((size_t)N*64*4));
  unsigned short* xh1 = (unsigned short*)(ws + A((size_t)N*64*2));
  unsigned short* xx1 = (unsigned short*)(ws + A((size_t)N*2));
  float* x2CN = (float*)(ws + A((size_t)N*64*4));
  unsigned short* xh2 = (unsigned short*)(ws + A((size_t)N*64*2));
  unsigned short* xx2 = (unsigned short*)(ws + A((size_t)N*2));
  float* x3CN = (float*)(ws + A((size_t)N*64*4));
  int* idxb = (int*)(ws + A((size_t)N*KNN_K*4));
  float* Ut  = (float*)(ws + A((size_t)N*64*4));
  float* Vtb = (float*)(ws + A((size_t)N*64*4));
  float* Ut2  = (float*)(ws + A((size_t)N*64*4));
  float* Vtb2 = (float*)(ws + A((size_t)N*64*4));
  float* w6t  = (float*)(ws + A((size_t)192*1024*4));
  float* w7xt = (float*)(ws + A((size_t)192*512*4));
  float* w8t  = (float*)(ws + A((size_t)512*256*4));
  float* gpart= (float*)(ws + A((size_t)1024*(N/64)*4));
  float* b7   = (float*)(ws + A((size_t)512*4));
  float* h7raw= (float*)(ws + A((size_t)512*N*4));
  float* h8   = (float*)(ws + A((size_t)256*N*4));
  if (off > ws_size) return;

  dim3 b256(256), b512(512);
  int nb0 = (N + 255) / 256;
  prep0<<<dim3(nb0 + 768 + 384 + 512), b256, 0, stream>>>(
      curr_pos, node_t, xh0, xx0, N, W1, bn1, Ut, Vtb, W6, w6t, W7, w7xt, W8, w8t);

  dim3 gknn(N/16);
  dim3 gec(N/16);
  dim3 gfin((N+255)/256);

  // round 1  (edge2 epilogue computes UV for round 2 from x1/W3/bn3)
  knn_mfma<32><<<gknn, b512, 0, stream>>>(xh0, xx0, idxb, N);
  edge2<true><<<gec, b256, 0, stream>>>(Ut, Vtb, idxb, W2, bn2, x1CN, xh1, xx1, N, W3, bn3, Ut2, Vtb2);
  // round 2
  knn_mfma<64><<<gknn, b512, 0, stream>>>(xh1, xx1, idxb, N);
  edge2<true><<<gec, b256, 0, stream>>>(Ut2, Vtb2, idxb, W4, bn4, x2CN, xh2, xx2, N, W5, bn5, Ut, Vtb);
  // round 3
  knn_mfma<64><<<gknn, b512, 0, stream>>>(xh2, xx2, idxb, N);
  edge2<false><<<gec, b256, 0, stream>>>(Ut, Vtb, idxb, nullptr, nullptr, x3CN, nullptr, nullptr, N, nullptr, nullptr, nullptr, nullptr);
  // head
  conv67<<<dim3(N/128, 24), b256, 0, stream>>>(w6t, w7xt, x1CN, x2CN, x3CN, bn6, gpart, h7raw, N);
  gmax_bias7<<<dim3(8), dim3(1024), 0, stream>>>(gpart, W7, b7, N/128);
  conv8w<<<dim3(N/128, 8), b256, 0, stream>>>(w8t, h7raw, b7, bn7, bn8, h8, N);
  w9_kernel<<<gfin, b256, 0, stream>>>(W9, h8, out, N);
}

// Round 27
// 524.988 us; speedup vs baseline: 1.0601x; 1.0252x over previous
//
#include <hip/hip_runtime.h>
#include <hip/hip_bf16.h>

#define KNN_K 20
typedef _Float16 f16;
typedef _Float16 half8 __attribute__((ext_vector_type(8)));
typedef float f32x4 __attribute__((ext_vector_type(4)));

__device__ __forceinline__ float lrelu(float x){ return x >= 0.f ? x : 0.2f*x; }
__device__ __forceinline__ f16 us2h(unsigned short u){ union{unsigned short u; f16 h;} x; x.u=u; return x.h; }
__device__ __forceinline__ unsigned short h2us(f16 h){ union{unsigned short u; f16 h;} x; x.h=h; return x.u; }

__device__ __forceinline__ unsigned pack_key16(f16 v, int m){
  unsigned u = h2us(v);
  unsigned s = (u & 0x8000u) ? ((~u) & 0xFFFFu) : (u | 0x8000u);
  return (s << 16) | ((~(unsigned)m) & 0xFFFFu);
}

__device__ __forceinline__ unsigned med3u(unsigned a, unsigned b, unsigned c){
  unsigned d;
  asm("v_med3_u32 %0, %1, %2, %3" : "=v"(d) : "v"(a), "v"(b), "v"(c));
  return d;
}

// Sorted-desc insert via median: tk'[j] = med3(tk[j-1], tk[j], key), reverse order
// (reads see OLD values; depth-1 dependencies; 20 ops). Exact.
__device__ __forceinline__ void insert_nc(unsigned* tk, unsigned key){
  #pragma unroll
  for (int j=KNN_K-1; j>=1; --j)
    tk[j] = med3u(tk[j-1], tk[j], key);
  tk[0] = max(tk[0], key);
}

__device__ __forceinline__ void merge_sorted(unsigned* tk, const unsigned* src){
  #pragma unroll
  for (int j=0;j<KNN_K;++j){
    unsigned key = src[j];
    if (key <= tk[KNN_K-1]) break;
    insert_nc(tk, key);
  }
}

// ---------------- prep0: x0 build + round-1 UV (fused) + all weight transposes ----------------
__global__ __launch_bounds__(256) void prep0(
    const float* __restrict__ pos, const int* __restrict__ nt,
    unsigned short* __restrict__ xh0, unsigned short* __restrict__ xx0, int N,
    const float* __restrict__ W1, const float* __restrict__ bn1,
    float* __restrict__ Ut, float* __restrict__ Vtb,
    const float* __restrict__ W6, float* __restrict__ w6t,
    const float* __restrict__ W7, float* __restrict__ w7xt,
    const float* __restrict__ W8, float* __restrict__ w8t)
{
  __shared__ float Wd[64][12], Wf[64][12];
  __shared__ float t1s[64], b1s[64], m1s[64];
  int b = blockIdx.x, tid = threadIdx.x;
  int nb0 = (N + 255) >> 8;
  if (b < nb0){
    for (int i = tid; i < 768; i += 256){
      int o = i / 12, c = i % 12;
      float wd = W1[(size_t)o*24 + c];
      Wd[o][c] = wd;
      Wf[o][c] = W1[(size_t)o*24 + 12 + c] - wd;
    }
    if (tid < 64){
      t1s[tid] = bn1[tid] / sqrtf(bn1[192+tid] + 1e-5f);
      b1s[tid] = bn1[64+tid];
      m1s[tid] = bn1[128+tid];
    }
    __syncthreads();
    int n = b*256 + tid;
    float v[12];
    v[0]=pos[n*3+0]; v[1]=pos[n*3+1]; v[2]=pos[n*3+2];
    int t = nt[n];
    #pragma unroll
    for (int c=0;c<9;++c) v[3+c] = (t==c) ? 1.f : 0.f;
    float xa = 0.f;
    #pragma unroll
    for (int c=0;c<12;++c){
      f16 h = (f16)v[c];
      float hf = (float)h;
      xh0[(size_t)n*32+c] = h2us(h);
      f16 pe = (f16)(hf*hf);
      xa += (float)pe;
    }
    #pragma unroll
    for (int c=12;c<32;++c) xh0[(size_t)n*32+c] = 0;
    xx0[n] = h2us((f16)xa);
    #pragma unroll 1
    for (int ob4=0; ob4<4; ++ob4){
      float aU[16], aV[16];
      #pragma unroll
      for (int i=0;i<16;++i){ aU[i]=0.f; aV[i]=0.f; }
      #pragma unroll 4
      for (int c2=0;c2<12;++c2){
        float xv = v[c2];
        #pragma unroll
        for (int i=0;i<16;++i){
          aU[i] = fmaf(Wd[ob4*16+i][c2], xv, aU[i]);
          aV[i] = fmaf(Wf[ob4*16+i][c2], xv, aV[i]);
        }
      }
      #pragma unroll
      for (int i=0;i<16;++i){
        int o = ob4*16 + i;
        float tt = t1s[o];
        Ut[(size_t)n*64 + o]  = aU[i]*tt;
        Vtb[(size_t)n*64 + o] = fmaf(aV[i] - m1s[o], tt, b1s[o]);
      }
    }
    return;
  }
  b -= nb0;
  if (b < 768){
    int i = b*256 + tid;
    int o = i / 192, c = i % 192;
    w6t[(size_t)c*1024 + o] = W6[(size_t)o*192 + c];
    return;
  }
  b -= 768;
  if (b < 384){
    int i = b*256 + tid;
    int o = i / 192, c = i % 192;
    w7xt[(size_t)c*512 + o] = W7[(size_t)o*1216 + 1024 + c];
    return;
  }
  b -= 384;
  {
    int i = b*256 + tid;
    int o = i / 512, c = i % 512;
    w8t[(size_t)c*256 + o] = W8[(size_t)o*512 + c];
  }
}

// ---------------- fused MFMA kNN (r25 config: med3 chain + 3-stage LDS merge, no SW pipe) ----------------
template<int C>
__global__ __launch_bounds__(512) void knn_mfma(
    const unsigned short* __restrict__ xh,
    const unsigned short* __restrict__ xx,
    int* __restrict__ idx, int N)
{
  __shared__ unsigned lists[32][16][KNN_K];
  __shared__ unsigned short xxs[8192];
  int tid = threadIdx.x;
  int w = tid >> 6, lane = tid & 63;
  int g = lane >> 4, c = lane & 15;
  int n0 = blockIdx.x * 16;
  int ntiles = N >> 6;

  ((uint4*)xxs)[tid]       = ((const uint4*)xx)[tid];
  ((uint4*)xxs)[tid + 512] = ((const uint4*)xx)[tid + 512];

  half8 bfrag[C/32];
  #pragma unroll
  for (int kc=0; kc<C/32; ++kc)
    bfrag[kc] = *reinterpret_cast<const half8*>(xh + (size_t)(n0 + c)*C + kc*32 + g*8);
  f16 qxx = us2h(xx[n0 + c]);
  __syncthreads();

  unsigned tk[KNN_K];
  #pragma unroll
  for (int j=0;j<KNN_K;++j) tk[j] = 0u;

  const unsigned short* ap = xh + (size_t)(w*64 + c)*C + g*8;
  int ml = w*64 + g*4;

  for (int t = w; t < ntiles; t += 8){
    #pragma unroll
    for (int msub=0; msub<4; ++msub){
      const unsigned short* ap2 = ap + msub*(16*C);
      f32x4 acc = {0.f,0.f,0.f,0.f};
      #pragma unroll
      for (int kc=0; kc<C/32; ++kc){
        half8 af = *reinterpret_cast<const half8*>(ap2 + kc*32);
        acc = __builtin_amdgcn_mfma_f32_16x16x32_f16(af, bfrag[kc], acc, 0, 0, 0);
      }
      #pragma unroll
      for (int j=0;j<4;++j){
        int mloc = ml + msub*16 + j;
        f16 dh = (f16)acc[j];
        f16 mi = dh * (f16)(-2.0f);
        f16 xm = us2h(xxs[mloc]);
        f16 t1 = (-xm) - mi;
        f16 pdh = t1 - qxx;
        insert_nc(tk, pack_key16(pdh, mloc));
      }
    }
    ap += (size_t)512*C;
    ml += 512;
  }

  {
    unsigned* dst = lists[w*4 + g][c];
    #pragma unroll
    for (int j=0;j<KNN_K;++j) dst[j] = tk[j];
  }
  __syncthreads();

  unsigned tk2[KNN_K];
  if (tid < 128){
    int n = tid >> 3, q = tid & 7;
    #pragma unroll
    for (int j=0;j<KNN_K;++j) tk2[j] = lists[q*4][n][j];
    for (int li=1; li<4; ++li) merge_sorted(tk2, lists[q*4 + li][n]);
  }
  __syncthreads();
  if (tid < 128){
    int n = tid >> 3, q = tid & 7;
    unsigned* dst = lists[q][n];
    #pragma unroll
    for (int j=0;j<KNN_K;++j) dst[j] = tk2[j];
  }
  __syncthreads();
  if (tid < 32){
    int n = tid >> 1, h = tid & 1;
    #pragma unroll
    for (int j=0;j<KNN_K;++j) tk2[j] = lists[h*4][n][j];
    for (int li=1; li<4; ++li) merge_sorted(tk2, lists[h*4 + li][n]);
  }
  __syncthreads();
  if (tid < 32){
    int n = tid >> 1, h = tid & 1;
    unsigned* dst = lists[h][n];
    #pragma unroll
    for (int j=0;j<KNN_K;++j) dst[j] = tk2[j];
  }
  __syncthreads();
  if (tid < 16){
    int n = tid;
    #pragma unroll
    for (int j=0;j<KNN_K;++j) tk2[j] = lists[0][n][j];
    merge_sorted(tk2, lists[1][n]);
    #pragma unroll
    for (int j=0;j<KNN_K;++j)
      idx[(size_t)(n0 + n)*KNN_K + j] = (int)((~tk2[j]) & 0xFFFFu);
  }
}

// ---------------- edge conv v5: 4 q's per wave ----------------
template<bool SECOND>
__global__ __launch_bounds__(256) void edge2(
    const float* __restrict__ Ut, const float* __restrict__ Vtb,
    const int* __restrict__ idx,
    const float* __restrict__ W2, const float* __restrict__ bn2,
    float* __restrict__ outCN, unsigned short* __restrict__ outh,
    unsigned short* __restrict__ outxx, int N,
    const float* __restrict__ Wn, const float* __restrict__ bnn,
    float* __restrict__ UtN, float* __restrict__ VtbN)
{
  __shared__ float eb[4][4][64];
  __shared__ float xb[16][64];
  int w = threadIdx.x >> 6, o = threadIdx.x & 63;
  float w2r[64]; float t2=0.f,b2=0.f,m2=0.f;
  if (SECOND){
    #pragma unroll
    for (int c4=0;c4<16;++c4){
      float4 wv = *reinterpret_cast<const float4*>(W2 + (size_t)o*64 + c4*4);
      w2r[c4*4+0]=wv.x; w2r[c4*4+1]=wv.y; w2r[c4*4+2]=wv.z; w2r[c4*4+3]=wv.w;
    }
    t2 = bn2[o]/sqrtf(bn2[192+o]+1e-5f); b2 = bn2[64+o]; m2 = bn2[128+o];
  }
  int nq = blockIdx.x*16 + w*4;
  float vo[4], u[4], best[4];
  const int* ip[4];
  int jj[4];
  #pragma unroll
  for (int q=0;q<4;++q){
    vo[q] = Vtb[(size_t)(nq+q)*64 + o];
    ip[q] = idx + (size_t)(nq+q)*KNN_K;
    jj[q] = ip[q][0];
    u[q]  = Ut[(size_t)jj[q]*64 + o];
    best[q] = -INFINITY;
  }
  #pragma unroll 1
  for (int k=0;k<KNN_K;++k){
    float uc[4];
    #pragma unroll
    for (int q=0;q<4;++q) uc[q] = u[q];
    if (k < KNN_K-1){
      #pragma unroll
      for (int q=0;q<4;++q){ jj[q] = ip[q][k+1]; u[q] = Ut[(size_t)jj[q]*64 + o]; }
    }
    float e[4];
    #pragma unroll
    for (int q=0;q<4;++q) e[q] = lrelu(uc[q] + vo[q]);
    if (SECOND){
      #pragma unroll
      for (int q=0;q<4;++q) eb[q][w][o] = e[q];
      float s0[4], s1[4], s2[4], s3[4];
      #pragma unroll
      for (int q=0;q<4;++q){ s0[q]=0.f; s1[q]=0.f; s2[q]=0.f; s3[q]=0.f; }
      #pragma unroll
      for (int c4=0;c4<16;++c4){
        #pragma unroll
        for (int q=0;q<4;++q){
          float4 ev = *reinterpret_cast<const float4*>(eb[q][w] + c4*4);
          s0[q] = fmaf(w2r[c4*4+0], ev.x, s0[q]);
          s1[q] = fmaf(w2r[c4*4+1], ev.y, s1[q]);
          s2[q] = fmaf(w2r[c4*4+2], ev.z, s2[q]);
          s3[q] = fmaf(w2r[c4*4+3], ev.w, s3[q]);
        }
      }
      #pragma unroll
      for (int q=0;q<4;++q){
        float s = (s0[q]+s1[q])+(s2[q]+s3[q]);
        best[q] = fmaxf(best[q], lrelu(fmaf(s - m2, t2, b2)));
      }
    } else {
      #pragma unroll
      for (int q=0;q<4;++q) best[q] = fmaxf(best[q], e[q]);
    }
  }
  #pragma unroll
  for (int q=0;q<4;++q) outCN[(size_t)o*N + nq + q] = best[q];
  if (SECOND){
    float p[4];
    #pragma unroll
    for (int q=0;q<4;++q){
      f16 h = (f16)best[q]; float hf = (float)h;
      outh[(size_t)(nq+q)*64 + o] = h2us(h);
      p[q] = (float)(f16)(hf*hf);
    }
    #pragma unroll
    for (int s2s=32;s2s>=1;s2s>>=1){
      #pragma unroll
      for (int q=0;q<4;++q) p[q] += __shfl_xor(p[q], s2s, 64);
    }
    if (o == 0){
      #pragma unroll
      for (int q=0;q<4;++q) outxx[nq+q] = h2us((f16)p[q]);
    }
    if (Wn){
      #pragma unroll
      for (int q=0;q<4;++q) xb[w*4+q][o] = best[q];
      float tn = bnn[o]/sqrtf(bnn[192+o]+1e-5f);
      float bb = bnn[64+o], mm = bnn[128+o];
      const float* wr = Wn + (size_t)o*128;
      float aU[4], aV[4];
      #pragma unroll
      for (int q=0;q<4;++q){ aU[q]=0.f; aV[q]=0.f; }
      #pragma unroll 8
      for (int c=0;c<64;++c){
        float wd = wr[c], wc = wr[64+c];
        float wdf = wc - wd;
        #pragma unroll
        for (int q=0;q<4;++q){
          float xv = xb[w*4+q][c];
          aU[q] = fmaf(wd, xv, aU[q]);
          aV[q] = fmaf(wdf, xv, aV[q]);
        }
      }
      #pragma unroll
      for (int q=0;q<4;++q){
        UtN[(size_t)(nq+q)*64 + o]  = aU[q]*tn;
        VtbN[(size_t)(nq+q)*64 + o] = fmaf(aV[q] - mm, tn, bb);
      }
    }
  }
}

// ---------------- conv67: conv6 (bn6+lrelu+gmax) and conv7-raw merged ----------------
__global__ __launch_bounds__(256) void conv67(
    const float* __restrict__ w6t, const float* __restrict__ w7xt,
    const float* __restrict__ sA, const float* __restrict__ sB, const float* __restrict__ sC,
    const float* __restrict__ bn6,
    float* __restrict__ gpart, float* __restrict__ h7raw, int N)
{
  __shared__ float ws[2][32][68];
  int tid = threadIdx.x;
  int ln = tid & 63;
  int og = (tid >> 6) * 16;
  int n0 = blockIdx.x*128;
  int y = blockIdx.y;
  bool six = (y < 16);
  int O  = six ? 1024 : 512;
  int ob = six ? y*64 : (y-16)*64;
  const float* WT = six ? w6t : w7xt;
  int n = n0 + ln*2;
  float a0[16], a1[16];
  #pragma unroll
  for (int i=0;i<16;++i){ a0[i]=0.f; a1[i]=0.f; }

  auto stage = [&](int m, int buf){
    int c0 = m*32;
    #pragma unroll
    for (int r=0;r<8;++r){
      int i = r*256 + tid;
      int cc = i >> 6, oo = i & 63;
      ws[buf][cc][oo] = WT[(size_t)(c0+cc)*O + ob + oo];
    }
  };
  auto srcrow = [&](int crow)->const float*{
    if (crow < 64) return sA + (size_t)crow*N;
    crow -= 64;
    if (crow < 64) return sB + (size_t)crow*N;
    crow -= 64;
    return sC + (size_t)crow*N;
  };

  stage(0, 0);
  __syncthreads();
  #pragma unroll 1
  for (int m=0; m<6; ++m){
    int buf = m & 1;
    if (m+1 < 6) stage(m+1, buf^1);
    const float* srow = srcrow(m*32);
    #pragma unroll 4
    for (int cc=0; cc<32; ++cc){
      float2 xv = *reinterpret_cast<const float2*>(srow + (size_t)cc*N + n);
      const float* wr = &ws[buf][cc][og];
      #pragma unroll
      for (int i=0;i<16;++i){
        a0[i] = fmaf(wr[i], xv.x, a0[i]);
        a1[i] = fmaf(wr[i], xv.y, a1[i]);
      }
    }
    __syncthreads();
  }
  if (six){
    #pragma unroll
    for (int i=0;i<16;++i){
      int oG = ob + og + i;
      float t = bn6[oG] / sqrtf(bn6[3*1024+oG] + 1e-5f);
      float mm = bn6[2*1024+oG], bb = bn6[1*1024+oG];
      a0[i] = lrelu(fmaf(a0[i] - mm, t, bb));
      a1[i] = lrelu(fmaf(a1[i] - mm, t, bb));
      float v = fmaxf(a0[i], a1[i]);
      #pragma unroll
      for (int s=32;s>=1;s>>=1) v = fmaxf(v, __shfl_xor(v, s, 64));
      if (ln == 0) gpart[(size_t)oG*gridDim.x + blockIdx.x] = v;
    }
  } else {
    #pragma unroll
    for (int i=0;i<16;++i){
      float2 st = {a0[i], a1[i]};
      *reinterpret_cast<float2*>(h7raw + (size_t)(ob+og+i)*N + n) = st;
    }
  }
}

// ---------------- gmax + W7 g-bias: 8 blocks, redundant gmax, identical per-o arithmetic ----------------
__global__ __launch_bounds__(1024) void gmax_bias7(
    const float* __restrict__ gpart, const float* __restrict__ W7,
    float* __restrict__ b7, int P)
{
  __shared__ float gs[1024];
  int t = threadIdx.x;
  float m = -INFINITY;
  for (int p=0;p<P;++p) m = fmaxf(m, gpart[(size_t)t*P + p]);
  gs[t] = m;
  __syncthreads();
  int w = t >> 6, ln = t & 63;
  #pragma unroll 1
  for (int oi=0; oi<4; ++oi){
    int o = blockIdx.x*64 + w*4 + oi;
    float a = 0.f;
    #pragma unroll
    for (int c0=0; c0<1024; c0+=64)
      a = fmaf(W7[(size_t)o*1216 + c0 + ln], gs[c0 + ln], a);
    #pragma unroll
    for (int s=32;s>=1;s>>=1) a += __shfl_xor(a, s, 64);
    if (ln == 0) b7[o] = a;
  }
}

// ---------------- conv8 v2: o-tile 32 x n-tile 128, y-grid 8 ----------------
__global__ __launch_bounds__(256) void conv8w(
    const float* __restrict__ w8t,
    const float* __restrict__ h7raw,
    const float* __restrict__ b7, const float* __restrict__ bn7,
    const float* __restrict__ bn8,
    float* __restrict__ h8, int N)
{
  __shared__ float ws[2][32][36];
  __shared__ float e7s[512], t7s[512], mm7s[512], bb7s[512];
  int tid = threadIdx.x;
  int ln = tid & 63;
  int og = (tid >> 6) * 8;
  int n0 = blockIdx.x*128;
  int ob = blockIdx.y*32;
  int n = n0 + ln*2;
  for (int c = tid; c < 512; c += 256){
    t7s[c]  = bn7[c] / sqrtf(bn7[3*512+c] + 1e-5f);
    bb7s[c] = bn7[512+c];
    mm7s[c] = bn7[2*512+c];
    e7s[c]  = b7[c];
  }
  float a0[8], a1[8];
  #pragma unroll
  for (int i=0;i<8;++i){ a0[i]=0.f; a1[i]=0.f; }

  auto stage = [&](int m, int buf){
    int c0 = m*32;
    #pragma unroll
    for (int r=0;r<4;++r){
      int i = r*256 + tid;
      int cc = i >> 5, oo = i & 31;
      ws[buf][cc][oo] = w8t[(size_t)(c0+cc)*256 + ob + oo];
    }
  };

  stage(0, 0);
  __syncthreads();
  #pragma unroll 1
  for (int m=0; m<16; ++m){
    int buf = m & 1;
    if (m+1 < 16) stage(m+1, buf^1);
    int c0 = m*32;
    #pragma unroll 4
    for (int cc=0; cc<32; ++cc){
      int c = c0 + cc;
      float2 raw = *reinterpret_cast<const float2*>(h7raw + (size_t)c*N + n);
      float e = e7s[c], mm = mm7s[c], t = t7s[c], bb = bb7s[c];
      float xv0 = lrelu(fmaf((raw.x + e) - mm, t, bb));
      float xv1 = lrelu(fmaf((raw.y + e) - mm, t, bb));
      const float* wr = &ws[buf][cc][og];
      #pragma unroll
      for (int i=0;i<8;++i){
        a0[i] = fmaf(wr[i], xv0, a0[i]);
        a1[i] = fmaf(wr[i], xv1, a1[i]);
      }
    }
    __syncthreads();
  }
  #pragma unroll
  for (int i=0;i<8;++i){
    int oG = ob + og + i;
    float t = bn8[oG] / sqrtf(bn8[3*256+oG] + 1e-5f);
    float mm = bn8[2*256+oG], bb = bn8[256+oG];
    a0[i] = lrelu(fmaf(a0[i] - mm, t, bb));
    a1[i] = lrelu(fmaf(a1[i] - mm, t, bb));
    float2 st = {a0[i], a1[i]};
    *reinterpret_cast<float2*>(h8 + (size_t)oG*N + n) = st;
  }
}

__global__ __launch_bounds__(256) void w9_kernel(
    const float* __restrict__ W9, const float* __restrict__ h8, float* __restrict__ out, int N)
{
  int n = blockIdx.x*256 + threadIdx.x;
  if (n >= N) return;
  float a0=0.f, a1=0.f, a2=0.f;
  for (int c=0;c<256;++c){
    float xv = h8[(size_t)c*N + n];
    a0 = fmaf(W9[c],       xv, a0);
    a1 = fmaf(W9[256+c],   xv, a1);
    a2 = fmaf(W9[512+c],   xv, a2);
  }
  out[(size_t)n*3+0]=a0; out[(size_t)n*3+1]=a1; out[(size_t)n*3+2]=a2;
}

extern "C" void kernel_launch(void* const* d_in, const int* in_sizes, int n_in,
                              void* d_out, int out_size, void* d_ws, size_t ws_size,
                              hipStream_t stream) {
  const float* curr_pos = (const float*)d_in[0];
  const int*   node_t   = (const int*)  d_in[1];
  const float* W1 = (const float*)d_in[2];
  const float* W2 = (const float*)d_in[3];
  const float* W3 = (const float*)d_in[4];
  const float* W4 = (const float*)d_in[5];
  const float* W5 = (const float*)d_in[6];
  const float* W6 = (const float*)d_in[7];
  const float* W7 = (const float*)d_in[8];
  const float* W8 = (const float*)d_in[9];
  const float* W9 = (const float*)d_in[10];
  const float* bn1 = (const float*)d_in[11];
  const float* bn2 = (const float*)d_in[12];
  const float* bn3 = (const float*)d_in[13];
  const float* bn4 = (const float*)d_in[14];
  const float* bn5 = (const float*)d_in[15];
  const float* bn6 = (const float*)d_in[16];
  const float* bn7 = (const float*)d_in[17];
  const float* bn8 = (const float*)d_in[18];
  float* out = (float*)d_out;

  const int N = in_sizes[0] / 3;

  char* ws = (char*)d_ws;
  size_t off = 0;
  auto A = [&](size_t b){ size_t o = off; off = (o + b + 255) & ~(size_t)255; return o; };

  unsigned short* xh0 = (unsigned short*)(ws + A((size_t)N*32*2));
  unsigned short* xx0 = (unsigned short*)(ws + A((size_t)N*2));
  float* x1CN = (float*)(ws + A((size_t)N*64*4));
  unsigned short* xh1 = (unsigned short*)(ws + A((size_t)N*64*2));
  unsigned short* xx1 = (unsigned short*)(ws + A((size_t)N*2));
  float* x2CN = (float*)(ws + A((size_t)N*64*4));
  unsigned short* xh2 = (unsigned short*)(ws + A((size_t)N*64*2));
  unsigned short* xx2 = (unsigned short*)(ws + A((size_t)N*2));
  float* x3CN = (float*)(ws + A((size_t)N*64*4));
  int* idxb = (int*)(ws + A((size_t)N*KNN_K*4));
  float* Ut  = (float*)(ws + A((size_t)N*64*4));
  float* Vtb = (float*)(ws + A((size_t)N*64*4));
  float* Ut2  = (float*)(ws + A((size_t)N*64*4));
  float* Vtb2 = (float*)(ws + A((size_t)N*64*4));
  float* w6t  = (float*)(ws + A((size_t)192*1024*4));
  float* w7xt = (float*)(ws + A((size_t)192*512*4));
  float* w8t  = (float*)(ws + A((size_t)512*256*4));
  float* gpart= (float*)(ws + A((size_t)1024*(N/64)*4));
  float* b7   = (float*)(ws + A((size_t)512*4));
  float* h7raw= (float*)(ws + A((size_t)512*N*4));
  float* h8   = (float*)(ws + A((size_t)256*N*4));
  if (off > ws_size) return;

  dim3 b256(256), b512(512);
  int nb0 = (N + 255) / 256;
  prep0<<<dim3(nb0 + 768 + 384 + 512), b256, 0, stream>>>(
      curr_pos, node_t, xh0, xx0, N, W1, bn1, Ut, Vtb, W6, w6t, W7, w7xt, W8, w8t);

  dim3 gknn(N/16);
  dim3 gec(N/16);
  dim3 gfin((N+255)/256);

  // round 1  (edge2 epilogue computes UV for round 2 from x1/W3/bn3)
  knn_mfma<32><<<gknn, b512, 0, stream>>>(xh0, xx0, idxb, N);
  edge2<true><<<gec, b256, 0, stream>>>(Ut, Vtb, idxb, W2, bn2, x1CN, xh1, xx1, N, W3, bn3, Ut2, Vtb2);
  // round 2
  knn_mfma<64><<<gknn, b512, 0, stream>>>(xh1, xx1, idxb, N);
  edge2<true><<<gec, b256, 0, stream>>>(Ut2, Vtb2, idxb, W4, bn4, x2CN, xh2, xx2, N, W5, bn5, Ut, Vtb);
  // round 3
  knn_mfma<64><<<gknn, b512, 0, stream>>>(xh2, xx2, idxb, N);
  edge2<false><<<gec, b256, 0, stream>>>(Ut, Vtb, idxb, nullptr, nullptr, x3CN, nullptr, nullptr, N, nullptr, nullptr, nullptr, nullptr);
  // head
  conv67<<<dim3(N/128, 24), b256, 0, stream>>>(w6t, w7xt, x1CN, x2CN, x3CN, bn6, gpart, h7raw, N);
  gmax_bias7<<<dim3(8), dim3(1024), 0, stream>>>(gpart, W7, b7, N/128);
  conv8w<<<dim3(N/128, 8), b256, 0, stream>>>(w8t, h7raw, b7, bn7, bn8, h8, N);
  w9_kernel<<<gfin, b256, 0, stream>>>(W9, h8, out, N);
}